// Round 12
// baseline (1505.413 us; speedup 1.0000x reference)
//
#include <hip/hip_runtime.h>
#include <math.h>

// ---------------- problem constants ----------------
constexpr int kB = 4;
constexpr int kS = 5440;           // 64*64 + 32*32 + 16*16 + 8*8
constexpr int kH = 256;            // HIDDEN
constexpr int kNH = 8, kNL = 4, kNP = 4, kDH = 32;
constexpr int kM = kB * kS;        // 21760 rows
constexpr int kCHSUM = 1408;       // sum(CHS)

typedef __attribute__((ext_vector_type(8))) short short8v;   // 8 bf16 (4 VGPRs)
typedef __attribute__((ext_vector_type(4))) short short4v;   // 4 bf16 (8 B)
typedef __attribute__((ext_vector_type(4))) float f32x4;
typedef __attribute__((ext_vector_type(16))) float f32x16;

__device__ inline short bf16rne(float f) {
    unsigned u = __float_as_uint(f);
    u += 0x7FFF + ((u >> 16) & 1);
    return (short)(u >> 16);
}
__device__ inline float bf2f(short s) {
    return __uint_as_float(((unsigned)(unsigned short)s) << 16);
}
// bijective XCD-chunked swizzle (m204): contiguous chunk per XCD
__device__ inline int xcd_swz(int orig, int nwg) {
    int q = nwg >> 3, r = nwg & 7;
    int x = orig & 7, o = orig >> 3;
    return (x < r ? x*(q+1) : r*(q+1) + (x-r)*q) + o;
}
// LDS offset with XOR swizzle: row stride 40 shorts, chunk in {0,8,16,24} shorts
#define LSWZ(row, chunk) ((row)*40 + ((chunk) ^ ((row) & 24)))

// ---------------- fused prep kernel (all weight conversions, 1 dispatch) ----------------
__device__ inline void cv4(const float* __restrict__ in, short* __restrict__ out, int q)
{
    int i = q * 4;
    f32x4 v = *(const f32x4*)(in + i);
    short4v o;
    o[0]=bf16rne(v[0]); o[1]=bf16rne(v[1]); o[2]=bf16rne(v[2]); o[3]=bf16rne(v[3]);
    *(short4v*)(out + i) = o;
}
__global__ __launch_bounds__(256) void prep_all_kernel(
        const float* __restrict__ off_w, const float* __restrict__ aw_w,
        const float* __restrict__ off_b, const float* __restrict__ aw_b,
        const float* __restrict__ val_w, const float* __restrict__ out_w,
        const float* __restrict__ ff1w, const float* __restrict__ ff2w,
        const float* __restrict__ pw0, const float* __restrict__ pw1,
        const float* __restrict__ pw2, const float* __restrict__ pw3,
        const float* __restrict__ c1w, const float* __restrict__ c2w,
        short* __restrict__ Wcat, float* __restrict__ bcat,
        short* __restrict__ valwb, short* __restrict__ outwb,
        short* __restrict__ ff1wb, short* __restrict__ ff2wb,
        short* __restrict__ pwb, short* __restrict__ c1wb, float* __restrict__ c2wr)
{
    int idx = blockIdx.x * 256 + threadIdx.x;
    if (idx < 589824) {                       // Wcat
        int col = idx & 255;
        int row = (idx >> 8) % 384;
        int i   = idx / (384*256);
        float v = (row < 256) ? off_w[((size_t)i*256 + row)*256 + col]
                              : aw_w[((size_t)i*128 + row-256)*256 + col];
        Wcat[idx] = bf16rne(v);
        return;
    }
    idx -= 589824;
    if (idx < 2304) {                         // bcat
        int row = idx % 384, i = idx / 384;
        bcat[idx] = (row < 256) ? off_b[i*256 + row] : aw_b[i*128 + row-256];
        return;
    }
    idx -= 2304;
    if (idx < 98304) { cv4(val_w, valwb, idx); return; }
    idx -= 98304;
    if (idx < 98304) { cv4(out_w, outwb, idx); return; }
    idx -= 98304;
    if (idx < 393216) { cv4(ff1w, ff1wb, idx); return; }
    idx -= 393216;
    if (idx < 393216) { cv4(ff2w, ff2wb, idx); return; }
    idx -= 393216;
    if (idx < 8192)  { cv4(pw0, pwb + 0,      idx); return; }
    idx -= 8192;
    if (idx < 16384) { cv4(pw1, pwb + 32768,  idx); return; }
    idx -= 16384;
    if (idx < 32768) { cv4(pw2, pwb + 98304,  idx); return; }
    idx -= 32768;
    if (idx < 32768) { cv4(pw3, pwb + 229376, idx); return; }
    idx -= 32768;
    if (idx < 147456) {                       // c1w reorder -> [o][(dy*3+dx)*256+c]
        int k = idx % 2304, o = idx / 2304;
        int kblk = k >> 8, c = k & 255;
        c1wb[idx] = bf16rne(c1w[(size_t)o*2304 + c*9 + kblk]);
        return;
    }
    idx -= 147456;
    if (idx < 1152) {                         // c2w reorder -> [o][9][64]
        int c = idx & 63, r = idx >> 6;
        int o = r / 9, kblk = r % 9;
        c2wr[idx] = c2w[((size_t)o*64 + c)*9 + kblk];
    }
}
constexpr int kPrepThreads = 589824+2304+98304+98304+393216+393216+8192+16384+32768+32768+147456+1152;

// ---------------- stage-1 kernels ----------------

__global__ __launch_bounds__(256) void fuseT_kernel(const float* __restrict__ f0,
        const float* __restrict__ f1, const float* __restrict__ f2,
        const float* __restrict__ tfw, short* __restrict__ out,
        int c, int hw, int prior)
{
    __shared__ float tile[32][33];
    int p0 = blockIdx.x * 32;
    int c0 = blockIdx.y * 32;
    int b  = blockIdx.z;
    int tx  = threadIdx.x & 31;
    int ty8 = threadIdx.x >> 5;
    #pragma unroll
    for (int i = 0; i < 4; ++i) {
        int ch = c0 + ty8 + i*8;
        float t0 = tfw[0*kCHSUM + prior + ch];
        float t1 = tfw[1*kCHSUM + prior + ch];
        float t2 = tfw[2*kCHSUM + prior + ch];
        float m = fmaxf(t0, fmaxf(t1, t2));
        float e0 = expf(t0-m), e1 = expf(t1-m), e2 = expf(t2-m);
        float inv = 1.0f / (e0+e1+e2);
        size_t base = ((size_t)b*c + ch)*hw + p0 + tx;
        tile[ty8+i*8][tx] = f0[base]*(e0*inv) + f1[base]*(e1*inv) + f2[base]*(e2*inv);
    }
    __syncthreads();
    #pragma unroll
    for (int i = 0; i < 4; ++i) {
        int p = p0 + ty8 + i*8;
        out[((size_t)b*hw + p)*c + c0 + tx] = bf16rne(tile[tx][ty8+i*8]);
    }
}

__global__ __launch_bounds__(256) void gn_sum_kernel(const float* __restrict__ xbufT,
        float* __restrict__ gnstat, int nchunks)
{
    int chunk = blockIdx.x, b = blockIdx.y;
    int t = threadIdx.x;
    size_t base = ((size_t)b*nchunks + chunk) * 4096;   // 16 rows * 256
    float s = 0.f, q = 0.f;
    #pragma unroll
    for (int i = 0; i < 4; ++i) {
        f32x4 v = *(const f32x4*)(xbufT + base + i*1024 + t*4);
        s += v[0]+v[1]+v[2]+v[3];
        q += v[0]*v[0]+v[1]*v[1]+v[2]*v[2]+v[3]*v[3];
    }
    __shared__ float ls[256], lq[256];
    ls[t] = s; lq[t] = q; __syncthreads();
    if (t < 64) { ls[t] += ls[t+64]+ls[t+128]+ls[t+192];
                  lq[t] += lq[t+64]+lq[t+128]+lq[t+192]; }
    __syncthreads();
    if (t < 32) {
        float ss = ls[2*t] + ls[2*t+1];
        float qq = lq[2*t] + lq[2*t+1];
        size_t o = (((size_t)b*nchunks + chunk)*32 + t)*2;
        gnstat[o] = ss; gnstat[o+1] = qq;
    }
}

__global__ __launch_bounds__(256) void gn_fin_kernel(const float* __restrict__ gnstat,
        const float* __restrict__ gg, const float* __restrict__ gb,
        float* __restrict__ gnA, float* __restrict__ gnB, int nchunks, int hw)
{
    int b = blockIdx.x, t = threadIdx.x;
    int g = t >> 3, sub = t & 7;
    float s = 0.f, q = 0.f;
    for (int c = sub; c < nchunks; c += 8) {
        size_t o = (((size_t)b*nchunks + c)*32 + g)*2;
        s += gnstat[o]; q += gnstat[o+1];
    }
    __shared__ float ls[256], lq[256], gmu[32], ginv[32];
    ls[t] = s; lq[t] = q; __syncthreads();
    if (sub < 4) { ls[t] += ls[t+4]; lq[t] += lq[t+4]; } __syncthreads();
    if (sub < 2) { ls[t] += ls[t+2]; lq[t] += lq[t+2]; } __syncthreads();
    if (sub == 0) {
        float ss = ls[t] + ls[t+1], qq = lq[t] + lq[t+1];
        float n = 8.0f * hw;
        float mu = ss / n;
        float var = qq / n - mu*mu;
        gmu[g] = mu; ginv[g] = rsqrtf(var + 1e-5f);
    }
    __syncthreads();
    int ch = t;
    float A = ginv[ch>>3] * gg[ch];
    float B = gb[ch] - gmu[ch>>3] * A;
    gnA[b*256 + ch] = A;
    gnB[b*256 + ch] = B;
}

__global__ __launch_bounds__(256) void gn_apply_kernel(const float* __restrict__ xbufT,
        const float* __restrict__ gnA, const float* __restrict__ gnB,
        const float* __restrict__ pos, float* __restrict__ src,
        short* __restrict__ srcbf, short* __restrict__ qbf, int hw, int sbase)
{
    int E = hw * 256;
    size_t fl = (size_t)blockIdx.x*1024 + threadIdx.x*4;
    int b = (int)(fl / E);
    int off = (int)(fl - (size_t)b*E);
    int p = off >> 8, col = off & 255;
    f32x4 v = *(const f32x4*)(xbufT + fl);
    f32x4 A = *(const f32x4*)(gnA + b*256 + col);
    f32x4 Bv = *(const f32x4*)(gnB + b*256 + col);
    size_t si = ((size_t)b*kS + sbase + p)*256 + col;
    f32x4 pv = *(const f32x4*)(pos + si);
    f32x4 o;
    o[0]=v[0]*A[0]+Bv[0]; o[1]=v[1]*A[1]+Bv[1];
    o[2]=v[2]*A[2]+Bv[2]; o[3]=v[3]*A[3]+Bv[3];
    *(f32x4*)(src + si) = o;
    short4v sb, qb;
    sb[0]=bf16rne(o[0]); sb[1]=bf16rne(o[1]); sb[2]=bf16rne(o[2]); sb[3]=bf16rne(o[3]);
    qb[0]=bf16rne(o[0]+pv[0]); qb[1]=bf16rne(o[1]+pv[1]);
    qb[2]=bf16rne(o[2]+pv[2]); qb[3]=bf16rne(o[3]+pv[3]);
    *(short4v*)(srcbf + si) = sb;
    *(short4v*)(qbf + si) = qb;
}

// single fused sine position embedding for all levels, broadcast over batch
__global__ __launch_bounds__(256) void pos_all_kernel(const float* __restrict__ lev,
                                                      float* __restrict__ pos)
{
    int idx = blockIdx.x * 256 + threadIdx.x;
    if (idx >= kS * 256) return;
    int ch = idx & 255;
    int p  = idx >> 8;
    int lvl, py, px, dim;
    if (p < 4096)      { lvl = 0; dim = 64; int l = p;        py = l >> 6; px = l & 63; }
    else if (p < 5120) { lvl = 1; dim = 32; int l = p - 4096; py = l >> 5; px = l & 31; }
    else if (p < 5376) { lvl = 2; dim = 16; int l = p - 5120; py = l >> 4; px = l & 15; }
    else               { lvl = 3; dim = 8;  int l = p - 5376; py = l >> 3; px = l & 7; }
    int c2 = ch & 127;
    int i  = c2 >> 1;
    float invdt = exp2f((float)i * -0.20762050593046015f);
    float t;
    if (ch < 128) t = (py + 1) / ((float)dim + 1e-6f) * 6.2831853071795864f;
    else          t = (px + 1) / ((float)dim + 1e-6f) * 6.2831853071795864f;
    float arg = t * invdt;
    float val = (c2 & 1) ? cosf(arg) : sinf(arg);
    val += lev[lvl*kH + ch];
    #pragma unroll
    for (int b = 0; b < kB; ++b)
        pos[(size_t)b*kS*256 + idx] = val;
}

// ---------------- BMx128 MFMA bf16 GEMM with 32x32x16 (BK=64) ----------------
template<int BM, int OUTMODE>
__global__ __launch_bounds__(256) void gemm32(const short* __restrict__ A,
        const short* __restrict__ W, const float* __restrict__ bias,
        float* __restrict__ C, short* __restrict__ Cb, int N, int K, int relu, int ncols)
{
    constexpr int FI = BM / 64;           // A frags per wave
    constexpr int NAV = (BM == 128) ? 4 : 2;
    __shared__ short Asm[2][BM * 40];
    __shared__ short Bsm[2][128 * 40];
    const int lin = xcd_swz(blockIdx.x, gridDim.x);
    const int bn  = (lin % ncols) * 128;
    const int bm  = (lin / ncols) * BM;
    const int t    = threadIdx.x;
    const int lane = t & 63;
    const int wid  = t >> 6;
    const int wr   = wid >> 1;
    const int wc   = wid & 1;
    const int l31  = lane & 31;
    const int hi8  = (lane >> 5) * 8;

    f32x16 acc[FI][2];
    #pragma unroll
    for (int i = 0; i < FI; ++i)
        #pragma unroll
        for (int j = 0; j < 2; ++j)
            acc[i][j] = (f32x16){0,0,0,0,0,0,0,0,0,0,0,0,0,0,0,0};

    int sa_r, sa_k;
    if constexpr (BM == 128) { sa_r = t >> 1; sa_k = (t & 1) * 32; }
    else                     { sa_r = t >> 2; sa_k = (t & 3) * 16; }
    const short* Aptr = A + (size_t)(bm + sa_r)*K + sa_k;
    const int sb_r = t >> 1;
    const int sb_k = (t & 1) * 32;
    const short* Wptr = W + (size_t)(bn + sb_r)*K + sb_k;

    short8v a[NAV], b[4];
    #pragma unroll
    for (int v = 0; v < NAV; ++v) a[v] = *(const short8v*)(Aptr + v*8);
    #pragma unroll
    for (int v = 0; v < 4; ++v)   b[v] = *(const short8v*)(Wptr + v*8);

    for (int k0 = 0; k0 < K; k0 += 64) {
        __syncthreads();
        if constexpr (BM == 128) {
            #pragma unroll
            for (int v = 0; v < 4; ++v) *(short8v*)&Asm[t & 1][LSWZ(sa_r, v*8)] = a[v];
        } else {
            #pragma unroll
            for (int v = 0; v < 2; ++v)
                *(short8v*)&Asm[sa_k >> 5][LSWZ(sa_r, (sa_k & 16) + v*8)] = a[v];
        }
        #pragma unroll
        for (int v = 0; v < 4; ++v) *(short8v*)&Bsm[t & 1][LSWZ(sb_r, v*8)] = b[v];
        __syncthreads();
        if (k0 + 64 < K) {
            #pragma unroll
            for (int v = 0; v < NAV; ++v) a[v] = *(const short8v*)(Aptr + k0 + 64 + v*8);
            #pragma unroll
            for (int v = 0; v < 4; ++v)   b[v] = *(const short8v*)(Wptr + k0 + 64 + v*8);
        }
        #pragma unroll
        for (int p = 0; p < 2; ++p)
            #pragma unroll
            for (int ks = 0; ks < 2; ++ks) {
                short8v af[FI], bfv[2];
                #pragma unroll
                for (int i = 0; i < FI; ++i)
                    af[i] = *(const short8v*)&Asm[p][LSWZ(wr*(BM/2) + i*32 + l31, ks*16 + hi8)];
                #pragma unroll
                for (int j = 0; j < 2; ++j)
                    bfv[j] = *(const short8v*)&Bsm[p][LSWZ(wc*64 + j*32 + l31, ks*16 + hi8)];
                #pragma unroll
                for (int i = 0; i < FI; ++i)
                    #pragma unroll
                    for (int j = 0; j < 2; ++j)
                        acc[i][j] = __builtin_amdgcn_mfma_f32_32x32x16_bf16(af[i], bfv[j], acc[i][j], 0, 0, 0);
            }
    }

    const int rbase = 4 * (lane >> 5);
    #pragma unroll
    for (int j = 0; j < 2; ++j) {
        int col = bn + wc*64 + j*32 + l31;
        float bz = bias[col];
        #pragma unroll
        for (int i = 0; i < FI; ++i) {
            int row0 = bm + wr*(BM/2) + i*32 + rbase;
            #pragma unroll
            for (int r = 0; r < 16; ++r) {
                int row = row0 + (r & 3) + 8*(r >> 2);
                float v = acc[i][j][r] + bz;
                if (relu) v = fmaxf(v, 0.f);
                if constexpr (OUTMODE == 0) C[(size_t)row*N + col] = v;
                else                        Cb[(size_t)row*N + col] = bf16rne(v);
            }
        }
    }
}

// ---------- fused GEMM (BM=64 x N=256) + residual add + LayerNorm epilogue ----------
// C = A(bf16,MxK) @ W(bf16,256xK)^T + bias; src = LN(src + C)*g + bta;
// writes src fp32, srcbf bf16, optionally qbf = bf16(src+pos). One block = 64 full rows.
template<int WQ>
__global__ __launch_bounds__(256) void gemm_ln(const short* __restrict__ A,
        const short* __restrict__ W, const float* __restrict__ bias,
        const float* __restrict__ g, const float* __restrict__ bta,
        float* __restrict__ src, short* __restrict__ srcbf,
        short* __restrict__ qbf, const float* __restrict__ pos, int K)
{
    __shared__ short Asm[2][64 * 40];
    __shared__ short Bsm[2][256 * 40];
    __shared__ float lred[2][2][2][16][2];   // [wr][wc][hi][r][{sum,sq}]
    const int t    = threadIdx.x;
    const int bm   = blockIdx.x * 64;
    const int lane = t & 63;
    const int wid  = t >> 6;
    const int wr   = wid >> 1;
    const int wc   = wid & 1;
    const int l31  = lane & 31;
    const int hi   = lane >> 5;
    const int hi8  = hi * 8;

    f32x16 acc[4];
    #pragma unroll
    for (int j = 0; j < 4; ++j)
        acc[j] = (f32x16){0,0,0,0,0,0,0,0,0,0,0,0,0,0,0,0};

    // A staging: 64 rows x 64k; thread: row t>>2, 16-short chunk (t&3)*16
    const int sa_r = t >> 2;
    const int sa_k = (t & 3) * 16;
    const short* Aptr = A + (size_t)(bm + sa_r)*K + sa_k;
    // B staging: 256 rows x 64k; thread: row t, all 64 shorts
    const short* Wptr = W + (size_t)t*K;

    short8v a[2], b[8];
    a[0] = *(const short8v*)(Aptr);
    a[1] = *(const short8v*)(Aptr + 8);
    #pragma unroll
    for (int v = 0; v < 8; ++v) b[v] = *(const short8v*)(Wptr + v*8);

    for (int k0 = 0; k0 < K; k0 += 64) {
        __syncthreads();
        *(short8v*)&Asm[sa_k >> 5][LSWZ(sa_r, (sa_k & 16) + 0)] = a[0];
        *(short8v*)&Asm[sa_k >> 5][LSWZ(sa_r, (sa_k & 16) + 8)] = a[1];
        #pragma unroll
        for (int v = 0; v < 8; ++v)
            *(short8v*)&Bsm[v >> 2][LSWZ(t, (v & 3)*8)] = b[v];
        __syncthreads();
        if (k0 + 64 < K) {
            a[0] = *(const short8v*)(Aptr + k0 + 64);
            a[1] = *(const short8v*)(Aptr + k0 + 72);
            #pragma unroll
            for (int v = 0; v < 8; ++v) b[v] = *(const short8v*)(Wptr + k0 + 64 + v*8);
        }
        #pragma unroll
        for (int p = 0; p < 2; ++p)
            #pragma unroll
            for (int ks = 0; ks < 2; ++ks) {
                short8v af = *(const short8v*)&Asm[p][LSWZ(wr*32 + l31, ks*16 + hi8)];
                short8v bfv[4];
                #pragma unroll
                for (int j = 0; j < 4; ++j)
                    bfv[j] = *(const short8v*)&Bsm[p][LSWZ(wc*128 + j*32 + l31, ks*16 + hi8)];
                #pragma unroll
                for (int j = 0; j < 4; ++j)
                    acc[j] = __builtin_amdgcn_mfma_f32_32x32x16_bf16(af, bfv[j], acc[j], 0, 0, 0);
            }
    }

    // epilogue: x = acc + bias + src; row = bm + wr*32 + 4*hi + (r&3)+8*(r>>2); col = wc*128+j*32+l31
    const int row0 = bm + wr*32 + 4*hi;
    float rsum[16], rsq[16];
    #pragma unroll
    for (int r = 0; r < 16; ++r) { rsum[r] = 0.f; rsq[r] = 0.f; }
    #pragma unroll
    for (int j = 0; j < 4; ++j) {
        int col = wc*128 + j*32 + l31;
        float bz = bias[col];
        #pragma unroll
        for (int r = 0; r < 16; ++r) {
            int row = row0 + (r & 3) + 8*(r >> 2);
            float x = acc[j][r] + bz + src[(size_t)row*256 + col];
            acc[j][r] = x;
            rsum[r] += x;
            rsq[r]  += x*x;
        }
    }
    #pragma unroll
    for (int o = 1; o < 32; o <<= 1) {
        #pragma unroll
        for (int r = 0; r < 16; ++r) {
            rsum[r] += __shfl_xor(rsum[r], o);
            rsq[r]  += __shfl_xor(rsq[r], o);
        }
    }
    if (l31 == 0) {
        #pragma unroll
        for (int r = 0; r < 16; ++r) {
            lred[wr][wc][hi][r][0] = rsum[r];
            lred[wr][wc][hi][r][1] = rsq[r];
        }
    }
    __syncthreads();
    float mu[16], inv[16];
    #pragma unroll
    for (int r = 0; r < 16; ++r) {
        float ts = rsum[r] + lred[wr][wc^1][hi][r][0];
        float tq = rsq[r]  + lred[wr][wc^1][hi][r][1];
        float m = ts * (1.f/256.f);
        mu[r] = m;
        inv[r] = rsqrtf(tq * (1.f/256.f) - m*m + 1e-5f);
    }
    #pragma unroll
    for (int j = 0; j < 4; ++j) {
        int col = wc*128 + j*32 + l31;
        float gv = g[col], bv = bta[col];
        #pragma unroll
        for (int r = 0; r < 16; ++r) {
            int row = row0 + (r & 3) + 8*(r >> 2);
            size_t si = (size_t)row*256 + col;
            float y = (acc[j][r] - mu[r]) * inv[r] * gv + bv;
            src[si] = y;
            srcbf[si] = bf16rne(y);
            if constexpr (WQ) qbf[si] = bf16rne(y + pos[si]);
        }
    }
}

// merged (off|aw|val) GEMM, 32x32x16, BM=128. 1-D grid 5*(kM/128), XCD-swizzled.
__global__ __launch_bounds__(256) void gemm_qv32(const short* __restrict__ Aq,
        const short* __restrict__ As, const short* __restrict__ W1,
        const short* __restrict__ W2, const float* __restrict__ b1,
        const float* __restrict__ b2, float* __restrict__ C1,
        short* __restrict__ Cb2)
{
    __shared__ short Asm[2][128 * 40];
    __shared__ short Bsm[2][128 * 40];
    const int lin = xcd_swz(blockIdx.x, gridDim.x);
    const int bn  = (lin % 5) * 128;
    const int bm  = (lin / 5) * 128;
    const bool qreg = bn < 384;
    const int K = 256;
    const int t    = threadIdx.x;
    const int lane = t & 63;
    const int wid  = t >> 6;
    const int wr   = wid >> 1;
    const int wc   = wid & 1;
    const int l31  = lane & 31;
    const int hi8  = (lane >> 5) * 8;
    const int sa_r = t >> 1;
    const int sa_p = t & 1;

    f32x16 acc[2][2];
    #pragma unroll
    for (int i = 0; i < 2; ++i)
        #pragma unroll
        for (int j = 0; j < 2; ++j)
            acc[i][j] = (f32x16){0,0,0,0,0,0,0,0,0,0,0,0,0,0,0,0};

    const short* Aptr = (qreg ? Aq : As) + (size_t)(bm + sa_r)*K + sa_p*32;
    const short* Wptr = (qreg ? (W1 + (size_t)(bn + sa_r)*K)
                              : (W2 + (size_t)(bn - 384 + sa_r)*K)) + sa_p*32;
    short8v a[4], b[4];
    #pragma unroll
    for (int v = 0; v < 4; ++v) { a[v] = *(const short8v*)(Aptr + v*8);
                                  b[v] = *(const short8v*)(Wptr + v*8); }

    for (int k0 = 0; k0 < K; k0 += 64) {
        __syncthreads();
        #pragma unroll
        for (int v = 0; v < 4; ++v) {
            *(short8v*)&Asm[sa_p][LSWZ(sa_r, v*8)] = a[v];
            *(short8v*)&Bsm[sa_p][LSWZ(sa_r, v*8)] = b[v];
        }
        __syncthreads();
        if (k0 + 64 < K) {
            #pragma unroll
            for (int v = 0; v < 4; ++v) {
                a[v] = *(const short8v*)(Aptr + k0 + 64 + v*8);
                b[v] = *(const short8v*)(Wptr + k0 + 64 + v*8);
            }
        }
        #pragma unroll
        for (int p = 0; p < 2; ++p)
            #pragma unroll
            for (int ks = 0; ks < 2; ++ks) {
                short8v af[2], bfv[2];
                #pragma unroll
                for (int i = 0; i < 2; ++i)
                    af[i] = *(const short8v*)&Asm[p][LSWZ(wr*64 + i*32 + l31, ks*16 + hi8)];
                #pragma unroll
                for (int j = 0; j < 2; ++j)
                    bfv[j] = *(const short8v*)&Bsm[p][LSWZ(wc*64 + j*32 + l31, ks*16 + hi8)];
                #pragma unroll
                for (int i = 0; i < 2; ++i)
                    #pragma unroll
                    for (int j = 0; j < 2; ++j)
                        acc[i][j] = __builtin_amdgcn_mfma_f32_32x32x16_bf16(af[i], bfv[j], acc[i][j], 0, 0, 0);
            }
    }

    const int rbase = 4 * (lane >> 5);
    if (bn == 256) {
        #pragma unroll
        for (int j = 0; j < 2; ++j) {
            int col = bn + wc*64 + j*32 + l31;
            float bz = b1[col];
            #pragma unroll
            for (int i = 0; i < 2; ++i) {
                int row0 = bm + wr*64 + i*32 + rbase;
                #pragma unroll
                for (int r = 0; r < 16; ++r) {
                    int row = row0 + (r & 3) + 8*(r >> 2);
                    float v = acc[i][j][r] + bz;
                    float m = v;
                    m = fmaxf(m, __shfl_xor(m, 1));
                    m = fmaxf(m, __shfl_xor(m, 2));
                    m = fmaxf(m, __shfl_xor(m, 4));
                    m = fmaxf(m, __shfl_xor(m, 8));
                    float e = expf(v - m);
                    float s = e;
                    s += __shfl_xor(s, 1);
                    s += __shfl_xor(s, 2);
                    s += __shfl_xor(s, 4);
                    s += __shfl_xor(s, 8);
                    C1[(size_t)row*384 + col] = e / s;
                }
            }
        }
    } else {
        #pragma unroll
        for (int j = 0; j < 2; ++j) {
            int col = bn + wc*64 + j*32 + l31;
            float bz = qreg ? b1[col] : b2[col - 384];
            #pragma unroll
            for (int i = 0; i < 2; ++i) {
                int row0 = bm + wr*64 + i*32 + rbase;
                #pragma unroll
                for (int r = 0; r < 16; ++r) {
                    int row = row0 + (r & 3) + 8*(r >> 2);
                    float v = acc[i][j][r] + bz;
                    if (qreg) C1[(size_t)row*384 + col] = v;
                    else      Cb2[(size_t)row*256 + col - 384] = bf16rne(v);
                }
            }
        }
    }
}

// implicit-GEMM conv1 (16x16 structure, BM=128xBN=64): A from srcbf with (dy,dx) shifts.
__global__ __launch_bounds__(256) void conv1_gemm_kernel(const short* __restrict__ srcbf,
        const short* __restrict__ Wr, const float* __restrict__ bias,
        float* __restrict__ C)
{
    __shared__ short Asm[2][128 * 40];
    __shared__ short Bsm[2][64 * 40];
    const int t    = threadIdx.x;
    const int bm   = blockIdx.x * 128;
    const int K    = 2304;
    const int lane = t & 63;
    const int wid  = t >> 6;
    const int wr   = wid >> 1;
    const int wc   = wid & 1;
    const int frow = lane & 15;
    const int g    = lane >> 4;
    const int sa_r = t >> 1;
    const int sa_p = t & 1;

    const int m  = bm + sa_r;
    const int bb = m >> 12, ys = (m >> 6) & 63, xs = m & 63;

    f32x4 acc[4][2];
    #pragma unroll
    for (int i = 0; i < 4; ++i)
        #pragma unroll
        for (int j = 0; j < 2; ++j)
            acc[i][j] = (f32x4){0.f,0.f,0.f,0.f};

    auto loadA = [&](int k0, short8v* r) {
        int kk = k0 + sa_p*32;
        int kblk = kk >> 8;
        int dyy = kblk / 3, dxx = kblk - dyy*3;
        int yy = ys + dyy - 1, xx = xs + dxx - 1;
        if (yy >= 0 && yy < 64 && xx >= 0 && xx < 64) {
            const short* p = srcbf + ((size_t)(bb*kS + yy*64 + xx))*256 + (kk & 255);
            #pragma unroll
            for (int v = 0; v < 4; ++v) r[v] = *(const short8v*)(p + v*8);
        } else {
            #pragma unroll
            for (int v = 0; v < 4; ++v) r[v] = (short8v){0,0,0,0,0,0,0,0};
        }
    };

    const int sb_r = t >> 2, sb_p = (t & 3) >> 1, sb_o = (t & 1) * 16;
    const short* Wptr = Wr + (size_t)sb_r*K + (t & 3)*16;
    short8v a[4], b[2];
    loadA(0, a);
    b[0] = *(const short8v*)Wptr;
    b[1] = *(const short8v*)(Wptr + 8);

    for (int k0 = 0; k0 < K; k0 += 64) {
        __syncthreads();
        #pragma unroll
        for (int v = 0; v < 4; ++v) *(short8v*)&Asm[sa_p][sa_r*40 + v*8] = a[v];
        *(short8v*)&Bsm[sb_p][sb_r*40 + sb_o]     = b[0];
        *(short8v*)&Bsm[sb_p][sb_r*40 + sb_o + 8] = b[1];
        __syncthreads();
        if (k0 + 64 < K) {
            loadA(k0 + 64, a);
            b[0] = *(const short8v*)(Wptr + k0 + 64);
            b[1] = *(const short8v*)(Wptr + k0 + 72);
        }
        #pragma unroll
        for (int p = 0; p < 2; ++p) {
            short8v af[4], bfv[2];
            #pragma unroll
            for (int i = 0; i < 4; ++i)
                af[i] = *(const short8v*)&Asm[p][(wr*64 + i*16 + frow)*40 + g*8];
            #pragma unroll
            for (int j = 0; j < 2; ++j)
                bfv[j] = *(const short8v*)&Bsm[p][(wc*32 + j*16 + frow)*40 + g*8];
            #pragma unroll
            for (int i = 0; i < 4; ++i)
                #pragma unroll
                for (int j = 0; j < 2; ++j)
                    acc[i][j] = __builtin_amdgcn_mfma_f32_16x16x32_bf16(af[i], bfv[j], acc[i][j], 0, 0, 0);
        }
    }

    #pragma unroll
    for (int j = 0; j < 2; ++j) {
        int col = wc*32 + j*16 + frow;       // N = 64
        float bz = bias[col];
        #pragma unroll
        for (int i = 0; i < 4; ++i) {
            int row = bm + wr*64 + i*16 + g*4;
            #pragma unroll
            for (int rr = 0; rr < 4; ++rr) {
                float v = fmaxf(acc[i][j][rr] + bz, 0.f);
                C[(size_t)(row + rr)*64 + col] = v;
            }
        }
    }
}

// ms_deform: d8 (4 threads/head), scalar FMAs (round-9 best), hoisted coords,
// branchless clamped taps, XCD-chunked blocks.
__global__ __launch_bounds__(256) void msdeform8_kernel(const short* __restrict__ val,
        const float* __restrict__ cat, short* __restrict__ msd)
{
    int blk  = xcd_swz(blockIdx.x, gridDim.x);
    int tid  = threadIdx.x;
    int d8   = tid & 3;
    int head = (tid >> 2) & 7;
    int bs   = blk*8 + (tid >> 5);
    int s  = bs % kS;
    int b  = bs / kS;
    float refx, refy;
    if (s < 4096)      { int loc = s;        refy = ((loc>>6)+0.5f)/64.f; refx = ((loc&63)+0.5f)/64.f; }
    else if (s < 5120) { int loc = s - 4096; refy = ((loc>>5)+0.5f)/32.f; refx = ((loc&31)+0.5f)/32.f; }
    else if (s < 5376) { int loc = s - 5120; refy = ((loc>>4)+0.5f)/16.f; refx = ((loc&15)+0.5f)/16.f; }
    else               { int loc = s - 5376; refy = ((loc>>3)+0.5f)/8.f;  refx = ((loc&7)+0.5f)/8.f; }
    const float* op = cat + (size_t)bs*384 + head*32;
    const float* ap = cat + (size_t)bs*384 + 256 + head*16;
    const short* vb = val + (size_t)b*kS*256 + head*32 + d8*8;
    const int WL[4] = {64,32,16,8};
    const int BASE[4] = {0,4096,5120,5376};
    float acc[8] = {0.f,0.f,0.f,0.f,0.f,0.f,0.f,0.f};
    #pragma unroll
    for (int l = 0; l < 4; ++l) {
        int wl = WL[l], base = BASE[l];
        float rxw = refx * wl - 0.5f;   // pow2-exact hoist
        float ryw = refy * wl - 0.5f;
        f32x4 o0 = *(const f32x4*)(op + l*8);
        f32x4 o1 = *(const f32x4*)(op + l*8 + 4);
        f32x4 av = *(const f32x4*)(ap + l*4);
        float oxs[4] = {o0[0], o0[2], o1[0], o1[2]};
        float oys[4] = {o0[1], o0[3], o1[1], o1[3]};
        #pragma unroll
        for (int p = 0; p < 4; ++p) {
            float gx = rxw + oxs[p];
            float gy = ryw + oys[p];
            float x0f = floorf(gx), y0f = floorf(gy);
            float wx1 = gx - x0f, wy1 = gy - y0f;
            int x0 = (int)x0f, y0 = (int)y0f;
            float a = av[p];
            #pragma unroll
            for (int dy = 0; dy < 2; ++dy) {
                int yi = y0 + dy;
                float wy = dy ? wy1 : 1.f - wy1;
                int vyok = (yi >= 0) & (yi < wl);
                int yc = min(max(yi, 0), wl - 1);
                #pragma unroll
                for (int dx = 0; dx < 2; ++dx) {
                    int xi = x0 + dx;
                    float wx = dx ? wx1 : 1.f - wx1;
                    int vok = vyok & (xi >= 0) & (xi < wl);
                    int xc = min(max(xi, 0), wl - 1);
                    float wgt = vok ? wx*wy*a : 0.f;
                    uint4 v = *(const uint4*)&vb[(size_t)(base + yc*wl + xc)*256];
                    acc[0] = fmaf(__uint_as_float(v.x << 16),          wgt, acc[0]);
                    acc[1] = fmaf(__uint_as_float(v.x & 0xffff0000u), wgt, acc[1]);
                    acc[2] = fmaf(__uint_as_float(v.y << 16),          wgt, acc[2]);
                    acc[3] = fmaf(__uint_as_float(v.y & 0xffff0000u), wgt, acc[3]);
                    acc[4] = fmaf(__uint_as_float(v.z << 16),          wgt, acc[4]);
                    acc[5] = fmaf(__uint_as_float(v.z & 0xffff0000u), wgt, acc[5]);
                    acc[6] = fmaf(__uint_as_float(v.w << 16),          wgt, acc[6]);
                    acc[7] = fmaf(__uint_as_float(v.w & 0xffff0000u), wgt, acc[7]);
                }
            }
        }
    }
    short8v o;
    #pragma unroll
    for (int k = 0; k < 8; ++k) o[k] = bf16rne(acc[k]);
    *(short8v*)&msd[(size_t)bs*256 + head*32 + d8*8] = o;
}

// conv2: 3x3, 64->2; input c1 NHWC fp32; weights reordered [o][9][64]; output NCHW
__global__ void conv2_kernel(const float* __restrict__ c1, const float* __restrict__ w,
                             const float* __restrict__ bias, float* __restrict__ pred)
{
    int idx = blockIdx.x * blockDim.x + threadIdx.x;   // B*2*64*64
    int x = idx & 63;
    int y = (idx >> 6) & 63;
    int o = (idx >> 12) & 1;
    int b = idx >> 13;
    float acc = bias[o];
    #pragma unroll
    for (int dy = 0; dy < 3; ++dy) {
        int yy = y + dy - 1;
        if (yy < 0 || yy >= 64) continue;
        #pragma unroll
        for (int dx = 0; dx < 3; ++dx) {
            int xx = x + dx - 1;
            if (xx < 0 || xx >= 64) continue;
            const f32x4* sp = (const f32x4*)(c1 + ((size_t)(b*4096) + yy*64 + xx)*64);
            const f32x4* wp = (const f32x4*)(w + (o*9 + dy*3 + dx)*64);
            #pragma unroll
            for (int c = 0; c < 16; ++c) {
                f32x4 sv = sp[c], wv = wp[c];
                acc += sv[0]*wv[0] + sv[1]*wv[1] + sv[2]*wv[2] + sv[3]*wv[3];
            }
        }
    }
    pred[idx] = acc;
}

// bilinear resize 64x64 -> 256x256 (half-pixel, edge clamp)
__global__ void resize_kernel(const float* __restrict__ pred, float* __restrict__ out)
{
    int idx = blockIdx.x * blockDim.x + threadIdx.x;   // B*2*256*256
    int X = idx & 255;
    int Y = (idx >> 8) & 255;
    int c = (idx >> 16) & 1;
    int b = idx >> 17;
    float sx = (X + 0.5f)*0.25f - 0.5f;
    float sy = (Y + 0.5f)*0.25f - 0.5f;
    int x0 = (int)floorf(sx); float fx = sx - x0;
    int y0 = (int)floorf(sy); float fy = sy - y0;
    int x0c = min(max(x0, 0), 63), x1c = min(max(x0+1, 0), 63);
    int y0c = min(max(y0, 0), 63), y1c = min(max(y0+1, 0), 63);
    const float* p = pred + ((size_t)(b*2 + c))*4096;
    float v00 = p[y0c*64 + x0c], v01 = p[y0c*64 + x1c];
    float v10 = p[y1c*64 + x0c], v11 = p[y1c*64 + x1c];
    out[idx] = (1.f-fy)*((1.f-fx)*v00 + fx*v01) + fy*((1.f-fx)*v10 + fx*v11);
}

// ---------------- launch ----------------
extern "C" void kernel_launch(void* const* d_in, const int* in_sizes, int n_in,
                              void* d_out, int out_size, void* d_ws, size_t ws_size,
                              hipStream_t stream)
{
    const float* F[3][4];
    for (int t = 0; t < 3; ++t)
        for (int l = 0; l < 4; ++l)
            F[t][l] = (const float*)d_in[t*4 + l];
    const float* tfw = (const float*)d_in[12];
    const float *pw[4], *pb[4], *gg[4], *gb[4];
    for (int l = 0; l < 4; ++l) {
        pw[l] = (const float*)d_in[13 + 4*l];
        pb[l] = (const float*)d_in[14 + 4*l];
        gg[l] = (const float*)d_in[15 + 4*l];
        gb[l] = (const float*)d_in[16 + 4*l];
    }
    const float* lev   = (const float*)d_in[29];
    const float* off_w = (const float*)d_in[30];
    const float* off_b = (const float*)d_in[31];
    const float* aw_w  = (const float*)d_in[32];
    const float* aw_b  = (const float*)d_in[33];
    const float* val_w = (const float*)d_in[34];
    const float* val_b = (const float*)d_in[35];
    const float* out_w = (const float*)d_in[36];
    const float* out_b = (const float*)d_in[37];
    const float* ln1g  = (const float*)d_in[38];
    const float* ln1b  = (const float*)d_in[39];
    const float* ff1w  = (const float*)d_in[40];
    const float* ff1b  = (const float*)d_in[41];
    const float* ff2w  = (const float*)d_in[42];
    const float* ff2b  = (const float*)d_in[43];
    const float* ln2g  = (const float*)d_in[44];
    const float* ln2b  = (const float*)d_in[45];
    const float* c1w   = (const float*)d_in[46];
    const float* c1b   = (const float*)d_in[47];
    const float* c2w   = (const float*)d_in[48];
    const float* c2b   = (const float*)d_in[49];

    const size_t N256 = (size_t)kB * kS * 256;        // 5,570,560
    float* ws    = (float*)d_ws;
    float* src   = ws;                                // 5.57M f
    short* srcbf = (short*)(src + N256);
    short* qbf   = srcbf + N256;
    short* valbf = qbf + N256;
    short* msdbf = valbf + N256;
    short* warena= msdbf + N256;                      // bf16 weights
    short* Wcat_bf = warena;                              // 589824
    short* valw_bf = Wcat_bf + 589824;                    // 393216
    short* outw_bf = valw_bf + 393216;                    // 393216
    short* ff1w_bf = outw_bf + 393216;                    // 1572864
    short* ff2w_bf = ff1w_bf + 1572864;                   // 1572864
    short* pw_bf   = ff2w_bf + 1572864;                   // 360448
    short* c1w_bf  = pw_bf + 360448;                      // 147456 (reordered)
    float* bcat  = (float*)(c1w_bf + 147456 + 128);   // 2304 f
    float* gnstat= bcat + 4096;                       // 65536 f
    float* gnA   = gnstat + 65536;                    // 1024 f
    float* gnB   = gnA + 1024;                        // 1024 f
    float* c2wr  = gnB + 1024;                        // 1152 f
    float* pos   = c2wr + 1280;                       // 5.57M f
    float* cat   = pos + N256;                        // kM*384
    float* tmp   = cat + (size_t)kM*384;              // 5.57M f (stage-1 xbufT)
    short* ffhbf = (short*)(tmp + N256);              // kM*1024 shorts
    // stage-1 aliases (cat/tmp dead in stage 1)
    short* fusedT = (short*)cat;
    float* xbufT  = tmp;
    // head aliases
    float* c1o   = (float*)valbf;                     // 16384*64 f (valbf+msdbf region)
    float* pred  = (float*)msdbf;

    const int LVL_HWS[4]  = {4096, 1024, 256, 64};
    const int LVL_BASE[4] = {0, 4096, 5120, 5376};
    const int LVL_C[4]    = {128, 256, 512, 512};
    const int LVL_PRIOR[4]= {0, 128, 256, 512};       // reference's literal (non-cumulative) priors
    const int PW_OFF[4]   = {0, 32768, 98304, 229376};

    // ---- fused weight prep (1 dispatch) ----
    prep_all_kernel<<<(kPrepThreads + 255)/256, 256, 0, stream>>>(
        off_w, aw_w, off_b, aw_b, val_w, out_w, ff1w, ff2w,
        pw[0], pw[1], pw[2], pw[3], c1w, c2w,
        Wcat_bf, bcat, valw_bf, outw_bf, ff1w_bf, ff2w_bf, pw_bf, c1w_bf, c2wr);

    // ---- stage 1 ----
    pos_all_kernel<<<(kS*256 + 255)/256, 256, 0, stream>>>(lev, pos);
    for (int l = 0; l < 4; ++l) {
        int hw = LVL_HWS[l], c = LVL_C[l];
        dim3 gf(hw/32, c/32, kB);
        fuseT_kernel<<<gf, 256, 0, stream>>>(F[0][l], F[1][l], F[2][l], tfw,
                                             fusedT, c, hw, LVL_PRIOR[l]);
        int nwg = 2 * (kB*hw/64);
        gemm32<64,0><<<nwg, 256, 0, stream>>>(fusedT, pw_bf + PW_OFF[l], pb[l],
                                              xbufT, nullptr, 256, c, 0, 2);
        int nchunks = hw / 16;
        gn_sum_kernel<<<dim3(nchunks, kB), 256, 0, stream>>>(xbufT, gnstat, nchunks);
        gn_fin_kernel<<<kB, 256, 0, stream>>>(gnstat, gg[l], gb[l], gnA, gnB, nchunks, hw);
        gn_apply_kernel<<<(kB*hw*256)/1024, 256, 0, stream>>>(xbufT, gnA, gnB, pos,
                                                              src, srcbf, qbf, hw, LVL_BASE[l]);
    }

    // ---- stage 2: 6 encoder layers ----
    for (int i = 0; i < 6; ++i) {
        gemm_qv32<<<5*(kM/128), 256, 0, stream>>>(qbf, srcbf,
                Wcat_bf + (size_t)i*384*256, valw_bf + (size_t)i*65536,
                bcat + i*384, val_b + i*256, cat, valbf);
        msdeform8_kernel<<<kM/8, 256, 0, stream>>>(valbf, cat, msdbf);
        gemm_ln<0><<<kM/64, 256, 0, stream>>>(msdbf, outw_bf + (size_t)i*65536,
                out_b + i*256, ln1g + i*256, ln1b + i*256,
                src, srcbf, nullptr, nullptr, 256);
        gemm32<128,1><<<8*(kM/128), 256, 0, stream>>>(srcbf, ff1w_bf + (size_t)i*262144,
                                                      ff1b + i*1024, nullptr, ffhbf, 1024, 256, 1, 8);
        gemm_ln<1><<<kM/64, 256, 0, stream>>>(ffhbf, ff2w_bf + (size_t)i*262144,
                ff2b + i*256, ln2g + i*256, ln2b + i*256,
                src, srcbf, qbf, pos, 1024);
    }

    // ---- stage 3: head ----
    {
        conv1_gemm_kernel<<<128, 256, 0, stream>>>(srcbf, c1w_bf, c1b, c1o);
        conv2_kernel<<<(kB*2*64*64)/256, 256, 0, stream>>>(c1o, c2wr, c2b, pred);
        resize_kernel<<<(kB*2*256*256)/256, 256, 0, stream>>>(pred, (float*)d_out);
    }
}

// Round 13
// 1100.497 us; speedup vs baseline: 1.3679x; 1.3679x over previous
//
#include <hip/hip_runtime.h>
#include <math.h>

// ---------------- problem constants ----------------
constexpr int kB = 4;
constexpr int kS = 5440;           // 64*64 + 32*32 + 16*16 + 8*8
constexpr int kH = 256;            // HIDDEN
constexpr int kNH = 8, kNL = 4, kNP = 4, kDH = 32;
constexpr int kM = kB * kS;        // 21760 rows
constexpr int kCHSUM = 1408;       // sum(CHS)

typedef __attribute__((ext_vector_type(8))) short short8v;   // 8 bf16 (4 VGPRs)
typedef __attribute__((ext_vector_type(4))) short short4v;   // 4 bf16 (8 B)
typedef __attribute__((ext_vector_type(4))) float f32x4;
typedef __attribute__((ext_vector_type(16))) float f32x16;

__device__ inline short bf16rne(float f) {
    unsigned u = __float_as_uint(f);
    u += 0x7FFF + ((u >> 16) & 1);
    return (short)(u >> 16);
}
__device__ inline float bf2f(short s) {
    return __uint_as_float(((unsigned)(unsigned short)s) << 16);
}
// bijective XCD-chunked swizzle (m204): contiguous chunk per XCD
__device__ inline int xcd_swz(int orig, int nwg) {
    int q = nwg >> 3, r = nwg & 7;
    int x = orig & 7, o = orig >> 3;
    return (x < r ? x*(q+1) : r*(q+1) + (x-r)*q) + o;
}
// LDS offset with XOR swizzle: row stride 40 shorts, chunk in {0,8,16,24} shorts
#define LSWZ(row, chunk) ((row)*40 + ((chunk) ^ ((row) & 24)))

// ---------------- fused prep kernel (all weight conversions, 1 dispatch) ----------------
__device__ inline void cv4(const float* __restrict__ in, short* __restrict__ out, int q)
{
    int i = q * 4;
    f32x4 v = *(const f32x4*)(in + i);
    short4v o;
    o[0]=bf16rne(v[0]); o[1]=bf16rne(v[1]); o[2]=bf16rne(v[2]); o[3]=bf16rne(v[3]);
    *(short4v*)(out + i) = o;
}
__global__ __launch_bounds__(256) void prep_all_kernel(
        const float* __restrict__ off_w, const float* __restrict__ aw_w,
        const float* __restrict__ off_b, const float* __restrict__ aw_b,
        const float* __restrict__ val_w, const float* __restrict__ out_w,
        const float* __restrict__ ff1w, const float* __restrict__ ff2w,
        const float* __restrict__ pw0, const float* __restrict__ pw1,
        const float* __restrict__ pw2, const float* __restrict__ pw3,
        const float* __restrict__ c1w, const float* __restrict__ c2w,
        short* __restrict__ Wcat, float* __restrict__ bcat,
        short* __restrict__ valwb, short* __restrict__ outwb,
        short* __restrict__ ff1wb, short* __restrict__ ff2wb,
        short* __restrict__ pwb, short* __restrict__ c1wb, float* __restrict__ c2wr)
{
    int idx = blockIdx.x * 256 + threadIdx.x;
    if (idx < 589824) {                       // Wcat
        int col = idx & 255;
        int row = (idx >> 8) % 384;
        int i   = idx / (384*256);
        float v = (row < 256) ? off_w[((size_t)i*256 + row)*256 + col]
                              : aw_w[((size_t)i*128 + row-256)*256 + col];
        Wcat[idx] = bf16rne(v);
        return;
    }
    idx -= 589824;
    if (idx < 2304) {                         // bcat
        int row = idx % 384, i = idx / 384;
        bcat[idx] = (row < 256) ? off_b[i*256 + row] : aw_b[i*128 + row-256];
        return;
    }
    idx -= 2304;
    if (idx < 98304) { cv4(val_w, valwb, idx); return; }
    idx -= 98304;
    if (idx < 98304) { cv4(out_w, outwb, idx); return; }
    idx -= 98304;
    if (idx < 393216) { cv4(ff1w, ff1wb, idx); return; }
    idx -= 393216;
    if (idx < 393216) { cv4(ff2w, ff2wb, idx); return; }
    idx -= 393216;
    if (idx < 8192)  { cv4(pw0, pwb + 0,      idx); return; }
    idx -= 8192;
    if (idx < 16384) { cv4(pw1, pwb + 32768,  idx); return; }
    idx -= 16384;
    if (idx < 32768) { cv4(pw2, pwb + 98304,  idx); return; }
    idx -= 32768;
    if (idx < 32768) { cv4(pw3, pwb + 229376, idx); return; }
    idx -= 32768;
    if (idx < 147456) {                       // c1w reorder -> [o][(dy*3+dx)*256+c]
        int k = idx % 2304, o = idx / 2304;
        int kblk = k >> 8, c = k & 255;
        c1wb[idx] = bf16rne(c1w[(size_t)o*2304 + c*9 + kblk]);
        return;
    }
    idx -= 147456;
    if (idx < 1152) {                         // c2w reorder -> [o][9][64]
        int c = idx & 63, r = idx >> 6;
        int o = r / 9, kblk = r % 9;
        c2wr[idx] = c2w[((size_t)o*64 + c)*9 + kblk];
    }
}
constexpr int kPrepThreads = 589824+2304+98304+98304+393216+393216+8192+16384+32768+32768+147456+1152;

// ---------------- stage-1 kernels ----------------

__global__ __launch_bounds__(256) void fuseT_kernel(const float* __restrict__ f0,
        const float* __restrict__ f1, const float* __restrict__ f2,
        const float* __restrict__ tfw, short* __restrict__ out,
        int c, int hw, int prior)
{
    __shared__ float tile[32][33];
    int p0 = blockIdx.x * 32;
    int c0 = blockIdx.y * 32;
    int b  = blockIdx.z;
    int tx  = threadIdx.x & 31;
    int ty8 = threadIdx.x >> 5;
    #pragma unroll
    for (int i = 0; i < 4; ++i) {
        int ch = c0 + ty8 + i*8;
        float t0 = tfw[0*kCHSUM + prior + ch];
        float t1 = tfw[1*kCHSUM + prior + ch];
        float t2 = tfw[2*kCHSUM + prior + ch];
        float m = fmaxf(t0, fmaxf(t1, t2));
        float e0 = expf(t0-m), e1 = expf(t1-m), e2 = expf(t2-m);
        float inv = 1.0f / (e0+e1+e2);
        size_t base = ((size_t)b*c + ch)*hw + p0 + tx;
        tile[ty8+i*8][tx] = f0[base]*(e0*inv) + f1[base]*(e1*inv) + f2[base]*(e2*inv);
    }
    __syncthreads();
    #pragma unroll
    for (int i = 0; i < 4; ++i) {
        int p = p0 + ty8 + i*8;
        out[((size_t)b*hw + p)*c + c0 + tx] = bf16rne(tile[tx][ty8+i*8]);
    }
}

__global__ __launch_bounds__(256) void gn_sum_kernel(const float* __restrict__ xbufT,
        float* __restrict__ gnstat, int nchunks)
{
    int chunk = blockIdx.x, b = blockIdx.y;
    int t = threadIdx.x;
    size_t base = ((size_t)b*nchunks + chunk) * 4096;   // 16 rows * 256
    float s = 0.f, q = 0.f;
    #pragma unroll
    for (int i = 0; i < 4; ++i) {
        f32x4 v = *(const f32x4*)(xbufT + base + i*1024 + t*4);
        s += v[0]+v[1]+v[2]+v[3];
        q += v[0]*v[0]+v[1]*v[1]+v[2]*v[2]+v[3]*v[3];
    }
    __shared__ float ls[256], lq[256];
    ls[t] = s; lq[t] = q; __syncthreads();
    if (t < 64) { ls[t] += ls[t+64]+ls[t+128]+ls[t+192];
                  lq[t] += lq[t+64]+lq[t+128]+lq[t+192]; }
    __syncthreads();
    if (t < 32) {
        float ss = ls[2*t] + ls[2*t+1];
        float qq = lq[2*t] + lq[2*t+1];
        size_t o = (((size_t)b*nchunks + chunk)*32 + t)*2;
        gnstat[o] = ss; gnstat[o+1] = qq;
    }
}

__global__ __launch_bounds__(256) void gn_fin_kernel(const float* __restrict__ gnstat,
        const float* __restrict__ gg, const float* __restrict__ gb,
        float* __restrict__ gnA, float* __restrict__ gnB, int nchunks, int hw)
{
    int b = blockIdx.x, t = threadIdx.x;
    int g = t >> 3, sub = t & 7;
    float s = 0.f, q = 0.f;
    for (int c = sub; c < nchunks; c += 8) {
        size_t o = (((size_t)b*nchunks + c)*32 + g)*2;
        s += gnstat[o]; q += gnstat[o+1];
    }
    __shared__ float ls[256], lq[256], gmu[32], ginv[32];
    ls[t] = s; lq[t] = q; __syncthreads();
    if (sub < 4) { ls[t] += ls[t+4]; lq[t] += lq[t+4]; } __syncthreads();
    if (sub < 2) { ls[t] += ls[t+2]; lq[t] += lq[t+2]; } __syncthreads();
    if (sub == 0) {
        float ss = ls[t] + ls[t+1], qq = lq[t] + lq[t+1];
        float n = 8.0f * hw;
        float mu = ss / n;
        float var = qq / n - mu*mu;
        gmu[g] = mu; ginv[g] = rsqrtf(var + 1e-5f);
    }
    __syncthreads();
    int ch = t;
    float A = ginv[ch>>3] * gg[ch];
    float B = gb[ch] - gmu[ch>>3] * A;
    gnA[b*256 + ch] = A;
    gnB[b*256 + ch] = B;
}

__global__ __launch_bounds__(256) void gn_apply_kernel(const float* __restrict__ xbufT,
        const float* __restrict__ gnA, const float* __restrict__ gnB,
        const float* __restrict__ pos, float* __restrict__ src,
        short* __restrict__ srcbf, short* __restrict__ qbf, int hw, int sbase)
{
    int E = hw * 256;
    size_t fl = (size_t)blockIdx.x*1024 + threadIdx.x*4;
    int b = (int)(fl / E);
    int off = (int)(fl - (size_t)b*E);
    int p = off >> 8, col = off & 255;
    f32x4 v = *(const f32x4*)(xbufT + fl);
    f32x4 A = *(const f32x4*)(gnA + b*256 + col);
    f32x4 Bv = *(const f32x4*)(gnB + b*256 + col);
    size_t si = ((size_t)b*kS + sbase + p)*256 + col;
    f32x4 pv = *(const f32x4*)(pos + si);
    f32x4 o;
    o[0]=v[0]*A[0]+Bv[0]; o[1]=v[1]*A[1]+Bv[1];
    o[2]=v[2]*A[2]+Bv[2]; o[3]=v[3]*A[3]+Bv[3];
    *(f32x4*)(src + si) = o;
    short4v sb, qb;
    sb[0]=bf16rne(o[0]); sb[1]=bf16rne(o[1]); sb[2]=bf16rne(o[2]); sb[3]=bf16rne(o[3]);
    qb[0]=bf16rne(o[0]+pv[0]); qb[1]=bf16rne(o[1]+pv[1]);
    qb[2]=bf16rne(o[2]+pv[2]); qb[3]=bf16rne(o[3]+pv[3]);
    *(short4v*)(srcbf + si) = sb;
    *(short4v*)(qbf + si) = qb;
}

// single fused sine position embedding for all levels, broadcast over batch
__global__ __launch_bounds__(256) void pos_all_kernel(const float* __restrict__ lev,
                                                      float* __restrict__ pos)
{
    int idx = blockIdx.x * 256 + threadIdx.x;
    if (idx >= kS * 256) return;
    int ch = idx & 255;
    int p  = idx >> 8;
    int lvl, py, px, dim;
    if (p < 4096)      { lvl = 0; dim = 64; int l = p;        py = l >> 6; px = l & 63; }
    else if (p < 5120) { lvl = 1; dim = 32; int l = p - 4096; py = l >> 5; px = l & 31; }
    else if (p < 5376) { lvl = 2; dim = 16; int l = p - 5120; py = l >> 4; px = l & 15; }
    else               { lvl = 3; dim = 8;  int l = p - 5376; py = l >> 3; px = l & 7; }
    int c2 = ch & 127;
    int i  = c2 >> 1;
    float invdt = exp2f((float)i * -0.20762050593046015f);
    float t;
    if (ch < 128) t = (py + 1) / ((float)dim + 1e-6f) * 6.2831853071795864f;
    else          t = (px + 1) / ((float)dim + 1e-6f) * 6.2831853071795864f;
    float arg = t * invdt;
    float val = (c2 & 1) ? cosf(arg) : sinf(arg);
    val += lev[lvl*kH + ch];
    #pragma unroll
    for (int b = 0; b < kB; ++b)
        pos[(size_t)b*kS*256 + idx] = val;
}

// ---------------- BMx128 MFMA bf16 GEMM with 32x32x16 (BK=64) ----------------
template<int BM, int OUTMODE>
__global__ __launch_bounds__(256) void gemm32(const short* __restrict__ A,
        const short* __restrict__ W, const float* __restrict__ bias,
        float* __restrict__ C, short* __restrict__ Cb, int N, int K, int relu, int ncols)
{
    constexpr int FI = BM / 64;           // A frags per wave
    constexpr int NAV = (BM == 128) ? 4 : 2;
    __shared__ short Asm[2][BM * 40];
    __shared__ short Bsm[2][128 * 40];
    const int lin = xcd_swz(blockIdx.x, gridDim.x);
    const int bn  = (lin % ncols) * 128;
    const int bm  = (lin / ncols) * BM;
    const int t    = threadIdx.x;
    const int lane = t & 63;
    const int wid  = t >> 6;
    const int wr   = wid >> 1;
    const int wc   = wid & 1;
    const int l31  = lane & 31;
    const int hi8  = (lane >> 5) * 8;

    f32x16 acc[FI][2];
    #pragma unroll
    for (int i = 0; i < FI; ++i)
        #pragma unroll
        for (int j = 0; j < 2; ++j)
            acc[i][j] = (f32x16){0,0,0,0,0,0,0,0,0,0,0,0,0,0,0,0};

    int sa_r, sa_k;
    if constexpr (BM == 128) { sa_r = t >> 1; sa_k = (t & 1) * 32; }
    else                     { sa_r = t >> 2; sa_k = (t & 3) * 16; }
    const short* Aptr = A + (size_t)(bm + sa_r)*K + sa_k;
    const int sb_r = t >> 1;
    const int sb_k = (t & 1) * 32;
    const short* Wptr = W + (size_t)(bn + sb_r)*K + sb_k;

    short8v a[NAV], b[4];
    #pragma unroll
    for (int v = 0; v < NAV; ++v) a[v] = *(const short8v*)(Aptr + v*8);
    #pragma unroll
    for (int v = 0; v < 4; ++v)   b[v] = *(const short8v*)(Wptr + v*8);

    for (int k0 = 0; k0 < K; k0 += 64) {
        __syncthreads();
        if constexpr (BM == 128) {
            #pragma unroll
            for (int v = 0; v < 4; ++v) *(short8v*)&Asm[t & 1][LSWZ(sa_r, v*8)] = a[v];
        } else {
            #pragma unroll
            for (int v = 0; v < 2; ++v)
                *(short8v*)&Asm[sa_k >> 5][LSWZ(sa_r, (sa_k & 16) + v*8)] = a[v];
        }
        #pragma unroll
        for (int v = 0; v < 4; ++v) *(short8v*)&Bsm[t & 1][LSWZ(sb_r, v*8)] = b[v];
        __syncthreads();
        if (k0 + 64 < K) {
            #pragma unroll
            for (int v = 0; v < NAV; ++v) a[v] = *(const short8v*)(Aptr + k0 + 64 + v*8);
            #pragma unroll
            for (int v = 0; v < 4; ++v)   b[v] = *(const short8v*)(Wptr + k0 + 64 + v*8);
        }
        #pragma unroll
        for (int p = 0; p < 2; ++p)
            #pragma unroll
            for (int ks = 0; ks < 2; ++ks) {
                short8v af[FI], bfv[2];
                #pragma unroll
                for (int i = 0; i < FI; ++i)
                    af[i] = *(const short8v*)&Asm[p][LSWZ(wr*(BM/2) + i*32 + l31, ks*16 + hi8)];
                #pragma unroll
                for (int j = 0; j < 2; ++j)
                    bfv[j] = *(const short8v*)&Bsm[p][LSWZ(wc*64 + j*32 + l31, ks*16 + hi8)];
                #pragma unroll
                for (int i = 0; i < FI; ++i)
                    #pragma unroll
                    for (int j = 0; j < 2; ++j)
                        acc[i][j] = __builtin_amdgcn_mfma_f32_32x32x16_bf16(af[i], bfv[j], acc[i][j], 0, 0, 0);
            }
    }

    const int rbase = 4 * (lane >> 5);
    #pragma unroll
    for (int j = 0; j < 2; ++j) {
        int col = bn + wc*64 + j*32 + l31;
        float bz = bias[col];
        #pragma unroll
        for (int i = 0; i < FI; ++i) {
            int row0 = bm + wr*(BM/2) + i*32 + rbase;
            #pragma unroll
            for (int r = 0; r < 16; ++r) {
                int row = row0 + (r & 3) + 8*(r >> 2);
                float v = acc[i][j][r] + bz;
                if (relu) v = fmaxf(v, 0.f);
                if constexpr (OUTMODE == 0) C[(size_t)row*N + col] = v;
                else                        Cb[(size_t)row*N + col] = bf16rne(v);
            }
        }
    }
}

// merged (off|aw|val) GEMM, 32x32x16, BM=128. 1-D grid 5*(kM/128), XCD-swizzled.
__global__ __launch_bounds__(256) void gemm_qv32(const short* __restrict__ Aq,
        const short* __restrict__ As, const short* __restrict__ W1,
        const short* __restrict__ W2, const float* __restrict__ b1,
        const float* __restrict__ b2, float* __restrict__ C1,
        short* __restrict__ Cb2)
{
    __shared__ short Asm[2][128 * 40];
    __shared__ short Bsm[2][128 * 40];
    const int lin = xcd_swz(blockIdx.x, gridDim.x);
    const int bn  = (lin % 5) * 128;
    const int bm  = (lin / 5) * 128;
    const bool qreg = bn < 384;
    const int K = 256;
    const int t    = threadIdx.x;
    const int lane = t & 63;
    const int wid  = t >> 6;
    const int wr   = wid >> 1;
    const int wc   = wid & 1;
    const int l31  = lane & 31;
    const int hi8  = (lane >> 5) * 8;
    const int sa_r = t >> 1;
    const int sa_p = t & 1;

    f32x16 acc[2][2];
    #pragma unroll
    for (int i = 0; i < 2; ++i)
        #pragma unroll
        for (int j = 0; j < 2; ++j)
            acc[i][j] = (f32x16){0,0,0,0,0,0,0,0,0,0,0,0,0,0,0,0};

    const short* Aptr = (qreg ? Aq : As) + (size_t)(bm + sa_r)*K + sa_p*32;
    const short* Wptr = (qreg ? (W1 + (size_t)(bn + sa_r)*K)
                              : (W2 + (size_t)(bn - 384 + sa_r)*K)) + sa_p*32;
    short8v a[4], b[4];
    #pragma unroll
    for (int v = 0; v < 4; ++v) { a[v] = *(const short8v*)(Aptr + v*8);
                                  b[v] = *(const short8v*)(Wptr + v*8); }

    for (int k0 = 0; k0 < K; k0 += 64) {
        __syncthreads();
        #pragma unroll
        for (int v = 0; v < 4; ++v) {
            *(short8v*)&Asm[sa_p][LSWZ(sa_r, v*8)] = a[v];
            *(short8v*)&Bsm[sa_p][LSWZ(sa_r, v*8)] = b[v];
        }
        __syncthreads();
        if (k0 + 64 < K) {
            #pragma unroll
            for (int v = 0; v < 4; ++v) {
                a[v] = *(const short8v*)(Aptr + k0 + 64 + v*8);
                b[v] = *(const short8v*)(Wptr + k0 + 64 + v*8);
            }
        }
        #pragma unroll
        for (int p = 0; p < 2; ++p)
            #pragma unroll
            for (int ks = 0; ks < 2; ++ks) {
                short8v af[2], bfv[2];
                #pragma unroll
                for (int i = 0; i < 2; ++i)
                    af[i] = *(const short8v*)&Asm[p][LSWZ(wr*64 + i*32 + l31, ks*16 + hi8)];
                #pragma unroll
                for (int j = 0; j < 2; ++j)
                    bfv[j] = *(const short8v*)&Bsm[p][LSWZ(wc*64 + j*32 + l31, ks*16 + hi8)];
                #pragma unroll
                for (int i = 0; i < 2; ++i)
                    #pragma unroll
                    for (int j = 0; j < 2; ++j)
                        acc[i][j] = __builtin_amdgcn_mfma_f32_32x32x16_bf16(af[i], bfv[j], acc[i][j], 0, 0, 0);
            }
    }

    const int rbase = 4 * (lane >> 5);
    if (bn == 256) {
        #pragma unroll
        for (int j = 0; j < 2; ++j) {
            int col = bn + wc*64 + j*32 + l31;
            float bz = b1[col];
            #pragma unroll
            for (int i = 0; i < 2; ++i) {
                int row0 = bm + wr*64 + i*32 + rbase;
                #pragma unroll
                for (int r = 0; r < 16; ++r) {
                    int row = row0 + (r & 3) + 8*(r >> 2);
                    float v = acc[i][j][r] + bz;
                    float m = v;
                    m = fmaxf(m, __shfl_xor(m, 1));
                    m = fmaxf(m, __shfl_xor(m, 2));
                    m = fmaxf(m, __shfl_xor(m, 4));
                    m = fmaxf(m, __shfl_xor(m, 8));
                    float e = expf(v - m);
                    float s = e;
                    s += __shfl_xor(s, 1);
                    s += __shfl_xor(s, 2);
                    s += __shfl_xor(s, 4);
                    s += __shfl_xor(s, 8);
                    C1[(size_t)row*384 + col] = e / s;
                }
            }
        }
    } else {
        #pragma unroll
        for (int j = 0; j < 2; ++j) {
            int col = bn + wc*64 + j*32 + l31;
            float bz = qreg ? b1[col] : b2[col - 384];
            #pragma unroll
            for (int i = 0; i < 2; ++i) {
                int row0 = bm + wr*64 + i*32 + rbase;
                #pragma unroll
                for (int r = 0; r < 16; ++r) {
                    int row = row0 + (r & 3) + 8*(r >> 2);
                    float v = acc[i][j][r] + bz;
                    if (qreg) C1[(size_t)row*384 + col] = v;
                    else      Cb2[(size_t)row*256 + col - 384] = bf16rne(v);
                }
            }
        }
    }
}

// implicit-GEMM conv1 (16x16 structure, BM=128xBN=64): A from srcbf with (dy,dx) shifts.
__global__ __launch_bounds__(256) void conv1_gemm_kernel(const short* __restrict__ srcbf,
        const short* __restrict__ Wr, const float* __restrict__ bias,
        float* __restrict__ C)
{
    __shared__ short Asm[2][128 * 40];
    __shared__ short Bsm[2][64 * 40];
    const int t    = threadIdx.x;
    const int bm   = blockIdx.x * 128;
    const int K    = 2304;
    const int lane = t & 63;
    const int wid  = t >> 6;
    const int wr   = wid >> 1;
    const int wc   = wid & 1;
    const int frow = lane & 15;
    const int g    = lane >> 4;
    const int sa_r = t >> 1;
    const int sa_p = t & 1;

    const int m  = bm + sa_r;
    const int bb = m >> 12, ys = (m >> 6) & 63, xs = m & 63;

    f32x4 acc[4][2];
    #pragma unroll
    for (int i = 0; i < 4; ++i)
        #pragma unroll
        for (int j = 0; j < 2; ++j)
            acc[i][j] = (f32x4){0.f,0.f,0.f,0.f};

    auto loadA = [&](int k0, short8v* r) {
        int kk = k0 + sa_p*32;
        int kblk = kk >> 8;
        int dyy = kblk / 3, dxx = kblk - dyy*3;
        int yy = ys + dyy - 1, xx = xs + dxx - 1;
        if (yy >= 0 && yy < 64 && xx >= 0 && xx < 64) {
            const short* p = srcbf + ((size_t)(bb*kS + yy*64 + xx))*256 + (kk & 255);
            #pragma unroll
            for (int v = 0; v < 4; ++v) r[v] = *(const short8v*)(p + v*8);
        } else {
            #pragma unroll
            for (int v = 0; v < 4; ++v) r[v] = (short8v){0,0,0,0,0,0,0,0};
        }
    };

    const int sb_r = t >> 2, sb_p = (t & 3) >> 1, sb_o = (t & 1) * 16;
    const short* Wptr = Wr + (size_t)sb_r*K + (t & 3)*16;
    short8v a[4], b[2];
    loadA(0, a);
    b[0] = *(const short8v*)Wptr;
    b[1] = *(const short8v*)(Wptr + 8);

    for (int k0 = 0; k0 < K; k0 += 64) {
        __syncthreads();
        #pragma unroll
        for (int v = 0; v < 4; ++v) *(short8v*)&Asm[sa_p][sa_r*40 + v*8] = a[v];
        *(short8v*)&Bsm[sb_p][sb_r*40 + sb_o]     = b[0];
        *(short8v*)&Bsm[sb_p][sb_r*40 + sb_o + 8] = b[1];
        __syncthreads();
        if (k0 + 64 < K) {
            loadA(k0 + 64, a);
            b[0] = *(const short8v*)(Wptr + k0 + 64);
            b[1] = *(const short8v*)(Wptr + k0 + 72);
        }
        #pragma unroll
        for (int p = 0; p < 2; ++p) {
            short8v af[4], bfv[2];
            #pragma unroll
            for (int i = 0; i < 4; ++i)
                af[i] = *(const short8v*)&Asm[p][(wr*64 + i*16 + frow)*40 + g*8];
            #pragma unroll
            for (int j = 0; j < 2; ++j)
                bfv[j] = *(const short8v*)&Bsm[p][(wc*32 + j*16 + frow)*40 + g*8];
            #pragma unroll
            for (int i = 0; i < 4; ++i)
                #pragma unroll
                for (int j = 0; j < 2; ++j)
                    acc[i][j] = __builtin_amdgcn_mfma_f32_16x16x32_bf16(af[i], bfv[j], acc[i][j], 0, 0, 0);
        }
    }

    #pragma unroll
    for (int j = 0; j < 2; ++j) {
        int col = wc*32 + j*16 + frow;       // N = 64
        float bz = bias[col];
        #pragma unroll
        for (int i = 0; i < 4; ++i) {
            int row = bm + wr*64 + i*16 + g*4;
            #pragma unroll
            for (int rr = 0; rr < 4; ++rr) {
                float v = fmaxf(acc[i][j][rr] + bz, 0.f);
                C[(size_t)(row + rr)*64 + col] = v;
            }
        }
    }
}

// ms_deform: d8 (4 threads/head), scalar FMAs (round-9 best), hoisted coords,
// branchless clamped taps, XCD-chunked blocks.
__global__ __launch_bounds__(256) void msdeform8_kernel(const short* __restrict__ val,
        const float* __restrict__ cat, short* __restrict__ msd)
{
    int blk  = xcd_swz(blockIdx.x, gridDim.x);
    int tid  = threadIdx.x;
    int d8   = tid & 3;
    int head = (tid >> 2) & 7;
    int bs   = blk*8 + (tid >> 5);
    int s  = bs % kS;
    int b  = bs / kS;
    float refx, refy;
    if (s < 4096)      { int loc = s;        refy = ((loc>>6)+0.5f)/64.f; refx = ((loc&63)+0.5f)/64.f; }
    else if (s < 5120) { int loc = s - 4096; refy = ((loc>>5)+0.5f)/32.f; refx = ((loc&31)+0.5f)/32.f; }
    else if (s < 5376) { int loc = s - 5120; refy = ((loc>>4)+0.5f)/16.f; refx = ((loc&15)+0.5f)/16.f; }
    else               { int loc = s - 5376; refy = ((loc>>3)+0.5f)/8.f;  refx = ((loc&7)+0.5f)/8.f; }
    const float* op = cat + (size_t)bs*384 + head*32;
    const float* ap = cat + (size_t)bs*384 + 256 + head*16;
    const short* vb = val + (size_t)b*kS*256 + head*32 + d8*8;
    const int WL[4] = {64,32,16,8};
    const int BASE[4] = {0,4096,5120,5376};
    float acc[8] = {0.f,0.f,0.f,0.f,0.f,0.f,0.f,0.f};
    #pragma unroll
    for (int l = 0; l < 4; ++l) {
        int wl = WL[l], base = BASE[l];
        float rxw = refx * wl - 0.5f;   // pow2-exact hoist
        float ryw = refy * wl - 0.5f;
        f32x4 o0 = *(const f32x4*)(op + l*8);
        f32x4 o1 = *(const f32x4*)(op + l*8 + 4);
        f32x4 av = *(const f32x4*)(ap + l*4);
        float oxs[4] = {o0[0], o0[2], o1[0], o1[2]};
        float oys[4] = {o0[1], o0[3], o1[1], o1[3]};
        #pragma unroll
        for (int p = 0; p < 4; ++p) {
            float gx = rxw + oxs[p];
            float gy = ryw + oys[p];
            float x0f = floorf(gx), y0f = floorf(gy);
            float wx1 = gx - x0f, wy1 = gy - y0f;
            int x0 = (int)x0f, y0 = (int)y0f;
            float a = av[p];
            #pragma unroll
            for (int dy = 0; dy < 2; ++dy) {
                int yi = y0 + dy;
                float wy = dy ? wy1 : 1.f - wy1;
                int vyok = (yi >= 0) & (yi < wl);
                int yc = min(max(yi, 0), wl - 1);
                #pragma unroll
                for (int dx = 0; dx < 2; ++dx) {
                    int xi = x0 + dx;
                    float wx = dx ? wx1 : 1.f - wx1;
                    int vok = vyok & (xi >= 0) & (xi < wl);
                    int xc = min(max(xi, 0), wl - 1);
                    float wgt = vok ? wx*wy*a : 0.f;
                    uint4 v = *(const uint4*)&vb[(size_t)(base + yc*wl + xc)*256];
                    acc[0] = fmaf(__uint_as_float(v.x << 16),          wgt, acc[0]);
                    acc[1] = fmaf(__uint_as_float(v.x & 0xffff0000u), wgt, acc[1]);
                    acc[2] = fmaf(__uint_as_float(v.y << 16),          wgt, acc[2]);
                    acc[3] = fmaf(__uint_as_float(v.y & 0xffff0000u), wgt, acc[3]);
                    acc[4] = fmaf(__uint_as_float(v.z << 16),          wgt, acc[4]);
                    acc[5] = fmaf(__uint_as_float(v.z & 0xffff0000u), wgt, acc[5]);
                    acc[6] = fmaf(__uint_as_float(v.w << 16),          wgt, acc[6]);
                    acc[7] = fmaf(__uint_as_float(v.w & 0xffff0000u), wgt, acc[7]);
                }
            }
        }
    }
    short8v o;
    #pragma unroll
    for (int k = 0; k < 8; ++k) o[k] = bf16rne(acc[k]);
    *(short8v*)&msd[(size_t)bs*256 + head*32 + d8*8] = o;
}

// src = LayerNorm(src + delta[bf16]); writes src fp32, srcbf, optionally qbf
template<int WQ>
__global__ __launch_bounds__(256) void add_ln_kernel(float* __restrict__ src,
        const short* __restrict__ delta, const float* __restrict__ g,
        const float* __restrict__ bta, short* __restrict__ srcbf,
        short* __restrict__ qbf, const float* __restrict__ pos)
{
    int lane = threadIdx.x & 63;
    int row  = blockIdx.x*4 + (threadIdx.x >> 6);
    f32x4* s4 = (f32x4*)(src + (size_t)row*256);
    f32x4 x = s4[lane];
    short4v dd = *(const short4v*)&delta[(size_t)row*256 + lane*4];
    x[0]+=bf2f(dd[0]); x[1]+=bf2f(dd[1]); x[2]+=bf2f(dd[2]); x[3]+=bf2f(dd[3]);
    float s = x[0]+x[1]+x[2]+x[3];
    #pragma unroll
    for (int o = 1; o < 64; o <<= 1) s += __shfl_xor(s, o);
    float mu = s * (1.f/256.f);
    f32x4 xc;
    xc[0]=x[0]-mu; xc[1]=x[1]-mu; xc[2]=x[2]-mu; xc[3]=x[3]-mu;
    float s2 = xc[0]*xc[0]+xc[1]*xc[1]+xc[2]*xc[2]+xc[3]*xc[3];
    #pragma unroll
    for (int o = 1; o < 64; o <<= 1) s2 += __shfl_xor(s2, o);
    float inv = rsqrtf(s2*(1.f/256.f) + 1e-5f);
    const f32x4 gv = ((const f32x4*)g)[lane];
    const f32x4 bv = ((const f32x4*)bta)[lane];
    f32x4 o4;
    o4[0]=xc[0]*inv*gv[0]+bv[0]; o4[1]=xc[1]*inv*gv[1]+bv[1];
    o4[2]=xc[2]*inv*gv[2]+bv[2]; o4[3]=xc[3]*inv*gv[3]+bv[3];
    s4[lane] = o4;
    short4v sb;
    sb[0]=bf16rne(o4[0]); sb[1]=bf16rne(o4[1]); sb[2]=bf16rne(o4[2]); sb[3]=bf16rne(o4[3]);
    *(short4v*)&srcbf[(size_t)row*256 + lane*4] = sb;
    if constexpr (WQ) {
        f32x4 pv = ((const f32x4*)(pos + (size_t)row*256))[lane];
        short4v qb;
        qb[0]=bf16rne(o4[0]+pv[0]); qb[1]=bf16rne(o4[1]+pv[1]);
        qb[2]=bf16rne(o4[2]+pv[2]); qb[3]=bf16rne(o4[3]+pv[3]);
        *(short4v*)&qbf[(size_t)row*256 + lane*4] = qb;
    }
}

// conv2: 3x3, 64->2; input c1 NHWC fp32; weights reordered [o][9][64]; output NCHW
__global__ void conv2_kernel(const float* __restrict__ c1, const float* __restrict__ w,
                             const float* __restrict__ bias, float* __restrict__ pred)
{
    int idx = blockIdx.x * blockDim.x + threadIdx.x;   // B*2*64*64
    int x = idx & 63;
    int y = (idx >> 6) & 63;
    int o = (idx >> 12) & 1;
    int b = idx >> 13;
    float acc = bias[o];
    #pragma unroll
    for (int dy = 0; dy < 3; ++dy) {
        int yy = y + dy - 1;
        if (yy < 0 || yy >= 64) continue;
        #pragma unroll
        for (int dx = 0; dx < 3; ++dx) {
            int xx = x + dx - 1;
            if (xx < 0 || xx >= 64) continue;
            const f32x4* sp = (const f32x4*)(c1 + ((size_t)(b*4096) + yy*64 + xx)*64);
            const f32x4* wp = (const f32x4*)(w + (o*9 + dy*3 + dx)*64);
            #pragma unroll
            for (int c = 0; c < 16; ++c) {
                f32x4 sv = sp[c], wv = wp[c];
                acc += sv[0]*wv[0] + sv[1]*wv[1] + sv[2]*wv[2] + sv[3]*wv[3];
            }
        }
    }
    pred[idx] = acc;
}

// bilinear resize 64x64 -> 256x256 (half-pixel, edge clamp)
__global__ void resize_kernel(const float* __restrict__ pred, float* __restrict__ out)
{
    int idx = blockIdx.x * blockDim.x + threadIdx.x;   // B*2*256*256
    int X = idx & 255;
    int Y = (idx >> 8) & 255;
    int c = (idx >> 16) & 1;
    int b = idx >> 17;
    float sx = (X + 0.5f)*0.25f - 0.5f;
    float sy = (Y + 0.5f)*0.25f - 0.5f;
    int x0 = (int)floorf(sx); float fx = sx - x0;
    int y0 = (int)floorf(sy); float fy = sy - y0;
    int x0c = min(max(x0, 0), 63), x1c = min(max(x0+1, 0), 63);
    int y0c = min(max(y0, 0), 63), y1c = min(max(y0+1, 0), 63);
    const float* p = pred + ((size_t)(b*2 + c))*4096;
    float v00 = p[y0c*64 + x0c], v01 = p[y0c*64 + x1c];
    float v10 = p[y1c*64 + x0c], v11 = p[y1c*64 + x1c];
    out[idx] = (1.f-fy)*((1.f-fx)*v00 + fx*v01) + fy*((1.f-fx)*v10 + fx*v11);
}

// ---------------- launch ----------------
extern "C" void kernel_launch(void* const* d_in, const int* in_sizes, int n_in,
                              void* d_out, int out_size, void* d_ws, size_t ws_size,
                              hipStream_t stream)
{
    const float* F[3][4];
    for (int t = 0; t < 3; ++t)
        for (int l = 0; l < 4; ++l)
            F[t][l] = (const float*)d_in[t*4 + l];
    const float* tfw = (const float*)d_in[12];
    const float *pw[4], *pb[4], *gg[4], *gb[4];
    for (int l = 0; l < 4; ++l) {
        pw[l] = (const float*)d_in[13 + 4*l];
        pb[l] = (const float*)d_in[14 + 4*l];
        gg[l] = (const float*)d_in[15 + 4*l];
        gb[l] = (const float*)d_in[16 + 4*l];
    }
    const float* lev   = (const float*)d_in[29];
    const float* off_w = (const float*)d_in[30];
    const float* off_b = (const float*)d_in[31];
    const float* aw_w  = (const float*)d_in[32];
    const float* aw_b  = (const float*)d_in[33];
    const float* val_w = (const float*)d_in[34];
    const float* val_b = (const float*)d_in[35];
    const float* out_w = (const float*)d_in[36];
    const float* out_b = (const float*)d_in[37];
    const float* ln1g  = (const float*)d_in[38];
    const float* ln1b  = (const float*)d_in[39];
    const float* ff1w  = (const float*)d_in[40];
    const float* ff1b  = (const float*)d_in[41];
    const float* ff2w  = (const float*)d_in[42];
    const float* ff2b  = (const float*)d_in[43];
    const float* ln2g  = (const float*)d_in[44];
    const float* ln2b  = (const float*)d_in[45];
    const float* c1w   = (const float*)d_in[46];
    const float* c1b   = (const float*)d_in[47];
    const float* c2w   = (const float*)d_in[48];
    const float* c2b   = (const float*)d_in[49];

    const size_t N256 = (size_t)kB * kS * 256;        // 5,570,560
    float* ws    = (float*)d_ws;
    float* src   = ws;                                // 5.57M f
    short* srcbf = (short*)(src + N256);
    short* qbf   = srcbf + N256;
    short* valbf = qbf + N256;
    short* msdbf = valbf + N256;
    short* warena= msdbf + N256;                      // bf16 weights
    short* Wcat_bf = warena;                              // 589824
    short* valw_bf = Wcat_bf + 589824;                    // 393216
    short* outw_bf = valw_bf + 393216;                    // 393216
    short* ff1w_bf = outw_bf + 393216;                    // 1572864
    short* ff2w_bf = ff1w_bf + 1572864;                   // 1572864
    short* pw_bf   = ff2w_bf + 1572864;                   // 360448
    short* c1w_bf  = pw_bf + 360448;                      // 147456 (reordered)
    float* bcat  = (float*)(c1w_bf + 147456 + 128);   // 2304 f
    float* gnstat= bcat + 4096;                       // 65536 f
    float* gnA   = gnstat + 65536;                    // 1024 f
    float* gnB   = gnA + 1024;                        // 1024 f
    float* c2wr  = gnB + 1024;                        // 1152 f
    float* pos   = c2wr + 1280;                       // 5.57M f
    float* cat   = pos + N256;                        // kM*384
    float* tmp   = cat + (size_t)kM*384;              // 5.57M f
    short* tmpbf = (short*)tmp;                       // bf16 view of tmp
    short* ffhbf = (short*)(tmp + N256);              // kM*1024 shorts
    // stage-1 aliases (cat/tmp dead in stage 1)
    short* fusedT = (short*)cat;
    float* xbufT  = tmp;
    // head aliases
    float* c1o   = (float*)valbf;                     // 16384*64 f (valbf+msdbf region)
    float* pred  = (float*)msdbf;

    const int LVL_HWS[4]  = {4096, 1024, 256, 64};
    const int LVL_BASE[4] = {0, 4096, 5120, 5376};
    const int LVL_C[4]    = {128, 256, 512, 512};
    const int LVL_PRIOR[4]= {0, 128, 256, 512};       // reference's literal (non-cumulative) priors
    const int PW_OFF[4]   = {0, 32768, 98304, 229376};

    // ---- fused weight prep (1 dispatch) ----
    prep_all_kernel<<<(kPrepThreads + 255)/256, 256, 0, stream>>>(
        off_w, aw_w, off_b, aw_b, val_w, out_w, ff1w, ff2w,
        pw[0], pw[1], pw[2], pw[3], c1w, c2w,
        Wcat_bf, bcat, valw_bf, outw_bf, ff1w_bf, ff2w_bf, pw_bf, c1w_bf, c2wr);

    // ---- stage 1 ----
    pos_all_kernel<<<(kS*256 + 255)/256, 256, 0, stream>>>(lev, pos);
    for (int l = 0; l < 4; ++l) {
        int hw = LVL_HWS[l], c = LVL_C[l];
        dim3 gf(hw/32, c/32, kB);
        fuseT_kernel<<<gf, 256, 0, stream>>>(F[0][l], F[1][l], F[2][l], tfw,
                                             fusedT, c, hw, LVL_PRIOR[l]);
        int nwg = 2 * (kB*hw/64);
        gemm32<64,0><<<nwg, 256, 0, stream>>>(fusedT, pw_bf + PW_OFF[l], pb[l],
                                              xbufT, nullptr, 256, c, 0, 2);
        int nchunks = hw / 16;
        gn_sum_kernel<<<dim3(nchunks, kB), 256, 0, stream>>>(xbufT, gnstat, nchunks);
        gn_fin_kernel<<<kB, 256, 0, stream>>>(gnstat, gg[l], gb[l], gnA, gnB, nchunks, hw);
        gn_apply_kernel<<<(kB*hw*256)/1024, 256, 0, stream>>>(xbufT, gnA, gnB, pos,
                                                              src, srcbf, qbf, hw, LVL_BASE[l]);
    }

    // ---- stage 2: 6 encoder layers ----
    for (int i = 0; i < 6; ++i) {
        gemm_qv32<<<5*(kM/128), 256, 0, stream>>>(qbf, srcbf,
                Wcat_bf + (size_t)i*384*256, valw_bf + (size_t)i*65536,
                bcat + i*384, val_b + i*256, cat, valbf);
        msdeform8_kernel<<<kM/8, 256, 0, stream>>>(valbf, cat, msdbf);
        gemm32<64,1><<<2*(kM/64), 256, 0, stream>>>(msdbf, outw_bf + (size_t)i*65536,
                                                    out_b + i*256, nullptr, tmpbf, 256, 256, 0, 2);
        add_ln_kernel<0><<<kM/4, 256, 0, stream>>>(src, tmpbf, ln1g + i*256, ln1b + i*256,
                                                   srcbf, nullptr, nullptr);
        gemm32<128,1><<<8*(kM/128), 256, 0, stream>>>(srcbf, ff1w_bf + (size_t)i*262144,
                                                      ff1b + i*1024, nullptr, ffhbf, 1024, 256, 1, 8);
        gemm32<64,1><<<2*(kM/64), 256, 0, stream>>>(ffhbf, ff2w_bf + (size_t)i*262144,
                                                    ff2b + i*256, nullptr, tmpbf, 256, 1024, 0, 2);
        add_ln_kernel<1><<<kM/4, 256, 0, stream>>>(src, tmpbf, ln2g + i*256, ln2b + i*256,
                                                   srcbf, qbf, pos);
    }

    // ---- stage 3: head ----
    {
        conv1_gemm_kernel<<<128, 256, 0, stream>>>(srcbf, c1w_bf, c1b, c1o);
        conv2_kernel<<<(kB*2*64*64)/256, 256, 0, stream>>>(c1o, c2wr, c2b, pred);
        resize_kernel<<<(kB*2*256*256)/256, 256, 0, stream>>>(pred, (float*)d_out);
    }
}

// Round 14
// 1068.726 us; speedup vs baseline: 1.4086x; 1.0297x over previous
//
#include <hip/hip_runtime.h>
#include <math.h>

// ---------------- problem constants ----------------
constexpr int kB = 4;
constexpr int kS = 5440;           // 64*64 + 32*32 + 16*16 + 8*8
constexpr int kH = 256;            // HIDDEN
constexpr int kNH = 8, kNL = 4, kNP = 4, kDH = 32;
constexpr int kM = kB * kS;        // 21760 rows
constexpr int kCHSUM = 1408;       // sum(CHS)
constexpr int kPad = 5936;         // padded S: 66^2 + 34^2 + 18^2 + 10^2
constexpr int kPadShorts = kB * kPad * 256;   // 6,078,464

typedef __attribute__((ext_vector_type(8))) short short8v;   // 8 bf16 (4 VGPRs)
typedef __attribute__((ext_vector_type(4))) short short4v;   // 4 bf16 (8 B)
typedef __attribute__((ext_vector_type(4))) float f32x4;
typedef __attribute__((ext_vector_type(16))) float f32x16;

__device__ inline short bf16rne(float f) {
    unsigned u = __float_as_uint(f);
    u += 0x7FFF + ((u >> 16) & 1);
    return (short)(u >> 16);
}
__device__ inline float bf2f(short s) {
    return __uint_as_float(((unsigned)(unsigned short)s) << 16);
}
// bijective XCD-chunked swizzle (m204): contiguous chunk per XCD
__device__ inline int xcd_swz(int orig, int nwg) {
    int q = nwg >> 3, r = nwg & 7;
    int x = orig & 7, o = orig >> 3;
    return (x < r ? x*(q+1) : r*(q+1) + (x-r)*q) + o;
}
// LDS offset with XOR swizzle: row stride 40 shorts, chunk in {0,8,16,24} shorts
#define LSWZ(row, chunk) ((row)*40 + ((chunk) ^ ((row) & 24)))

// ---------------- fused prep kernel (all weight conversions + lut + valpad zero) ----
__device__ inline void cv4(const float* __restrict__ in, short* __restrict__ out, int q)
{
    int i = q * 4;
    f32x4 v = *(const f32x4*)(in + i);
    short4v o;
    o[0]=bf16rne(v[0]); o[1]=bf16rne(v[1]); o[2]=bf16rne(v[2]); o[3]=bf16rne(v[3]);
    *(short4v*)(out + i) = o;
}
__global__ __launch_bounds__(256) void prep_all_kernel(
        const float* __restrict__ off_w, const float* __restrict__ aw_w,
        const float* __restrict__ off_b, const float* __restrict__ aw_b,
        const float* __restrict__ val_w, const float* __restrict__ out_w,
        const float* __restrict__ ff1w, const float* __restrict__ ff2w,
        const float* __restrict__ pw0, const float* __restrict__ pw1,
        const float* __restrict__ pw2, const float* __restrict__ pw3,
        const float* __restrict__ c1w, const float* __restrict__ c2w,
        short* __restrict__ Wcat, float* __restrict__ bcat,
        short* __restrict__ valwb, short* __restrict__ outwb,
        short* __restrict__ ff1wb, short* __restrict__ ff2wb,
        short* __restrict__ pwb, short* __restrict__ c1wb, float* __restrict__ c2wr,
        int* __restrict__ msdlut, short* __restrict__ valpad)
{
    int idx = blockIdx.x * 256 + threadIdx.x;
    if (idx < 589824) {                       // Wcat
        int col = idx & 255;
        int row = (idx >> 8) % 384;
        int i   = idx / (384*256);
        float v = (row < 256) ? off_w[((size_t)i*256 + row)*256 + col]
                              : aw_w[((size_t)i*128 + row-256)*256 + col];
        Wcat[idx] = bf16rne(v);
        return;
    }
    idx -= 589824;
    if (idx < 2304) {                         // bcat
        int row = idx % 384, i = idx / 384;
        bcat[idx] = (row < 256) ? off_b[i*256 + row] : aw_b[i*128 + row-256];
        return;
    }
    idx -= 2304;
    if (idx < 98304) { cv4(val_w, valwb, idx); return; }
    idx -= 98304;
    if (idx < 98304) { cv4(out_w, outwb, idx); return; }
    idx -= 98304;
    if (idx < 393216) { cv4(ff1w, ff1wb, idx); return; }
    idx -= 393216;
    if (idx < 393216) { cv4(ff2w, ff2wb, idx); return; }
    idx -= 393216;
    if (idx < 8192)  { cv4(pw0, pwb + 0,      idx); return; }
    idx -= 8192;
    if (idx < 16384) { cv4(pw1, pwb + 32768,  idx); return; }
    idx -= 16384;
    if (idx < 32768) { cv4(pw2, pwb + 98304,  idx); return; }
    idx -= 32768;
    if (idx < 32768) { cv4(pw3, pwb + 229376, idx); return; }
    idx -= 32768;
    if (idx < 147456) {                       // c1w reorder -> [o][(dy*3+dx)*256+c]
        int k = idx % 2304, o = idx / 2304;
        int kblk = k >> 8, c = k & 255;
        c1wb[idx] = bf16rne(c1w[(size_t)o*2304 + c*9 + kblk]);
        return;
    }
    idx -= 147456;
    if (idx < 1152) {                         // c2w reorder -> [o][9][64]
        int c = idx & 63, r = idx >> 6;
        int o = r / 9, kblk = r % 9;
        c2wr[idx] = c2w[((size_t)o*64 + c)*9 + kblk];
        return;
    }
    idx -= 1152;
    if (idx < kM) {                           // msdlut: bs -> padded row index
        int bs = idx;
        int b = bs / kS;
        int s = bs - b*kS;
        int pbase, wl2, py, px;
        if (s < 4096)      { pbase = 0;    wl2 = 66; int lo = s;        py = lo>>6; px = lo&63; }
        else if (s < 5120) { pbase = 4356; wl2 = 34; int lo = s - 4096; py = lo>>5; px = lo&31; }
        else if (s < 5376) { pbase = 5512; wl2 = 18; int lo = s - 5120; py = lo>>4; px = lo&15; }
        else               { pbase = 5836; wl2 = 10; int lo = s - 5376; py = lo>>3; px = lo&7; }
        msdlut[bs] = b*kPad + pbase + (py+1)*wl2 + (px+1);
        return;
    }
    idx -= kM;
    if (idx < kPadShorts/8) {                 // zero valpad (borders stay zero forever)
        short8v z = (short8v){0,0,0,0,0,0,0,0};
        *(short8v*)(valpad + (size_t)idx*8) = z;
    }
}
constexpr int kPrepThreads = 589824+2304+98304+98304+393216+393216+8192+16384+32768+32768+147456+1152
                           + kM + kPadShorts/8;

// ---------------- stage-1 kernels ----------------

__global__ __launch_bounds__(256) void fuseT_kernel(const float* __restrict__ f0,
        const float* __restrict__ f1, const float* __restrict__ f2,
        const float* __restrict__ tfw, short* __restrict__ out,
        int c, int hw, int prior)
{
    __shared__ float tile[32][33];
    int p0 = blockIdx.x * 32;
    int c0 = blockIdx.y * 32;
    int b  = blockIdx.z;
    int tx  = threadIdx.x & 31;
    int ty8 = threadIdx.x >> 5;
    #pragma unroll
    for (int i = 0; i < 4; ++i) {
        int ch = c0 + ty8 + i*8;
        float t0 = tfw[0*kCHSUM + prior + ch];
        float t1 = tfw[1*kCHSUM + prior + ch];
        float t2 = tfw[2*kCHSUM + prior + ch];
        float m = fmaxf(t0, fmaxf(t1, t2));
        float e0 = expf(t0-m), e1 = expf(t1-m), e2 = expf(t2-m);
        float inv = 1.0f / (e0+e1+e2);
        size_t base = ((size_t)b*c + ch)*hw + p0 + tx;
        tile[ty8+i*8][tx] = f0[base]*(e0*inv) + f1[base]*(e1*inv) + f2[base]*(e2*inv);
    }
    __syncthreads();
    #pragma unroll
    for (int i = 0; i < 4; ++i) {
        int p = p0 + ty8 + i*8;
        out[((size_t)b*hw + p)*c + c0 + tx] = bf16rne(tile[tx][ty8+i*8]);
    }
}

__global__ __launch_bounds__(256) void gn_sum_kernel(const float* __restrict__ xbufT,
        float* __restrict__ gnstat, int nchunks)
{
    int chunk = blockIdx.x, b = blockIdx.y;
    int t = threadIdx.x;
    size_t base = ((size_t)b*nchunks + chunk) * 4096;   // 16 rows * 256
    float s = 0.f, q = 0.f;
    #pragma unroll
    for (int i = 0; i < 4; ++i) {
        f32x4 v = *(const f32x4*)(xbufT + base + i*1024 + t*4);
        s += v[0]+v[1]+v[2]+v[3];
        q += v[0]*v[0]+v[1]*v[1]+v[2]*v[2]+v[3]*v[3];
    }
    __shared__ float ls[256], lq[256];
    ls[t] = s; lq[t] = q; __syncthreads();
    if (t < 64) { ls[t] += ls[t+64]+ls[t+128]+ls[t+192];
                  lq[t] += lq[t+64]+lq[t+128]+lq[t+192]; }
    __syncthreads();
    if (t < 32) {
        float ss = ls[2*t] + ls[2*t+1];
        float qq = lq[2*t] + lq[2*t+1];
        size_t o = (((size_t)b*nchunks + chunk)*32 + t)*2;
        gnstat[o] = ss; gnstat[o+1] = qq;
    }
}

__global__ __launch_bounds__(256) void gn_fin_kernel(const float* __restrict__ gnstat,
        const float* __restrict__ gg, const float* __restrict__ gb,
        float* __restrict__ gnA, float* __restrict__ gnB, int nchunks, int hw)
{
    int b = blockIdx.x, t = threadIdx.x;
    int g = t >> 3, sub = t & 7;
    float s = 0.f, q = 0.f;
    for (int c = sub; c < nchunks; c += 8) {
        size_t o = (((size_t)b*nchunks + c)*32 + g)*2;
        s += gnstat[o]; q += gnstat[o+1];
    }
    __shared__ float ls[256], lq[256], gmu[32], ginv[32];
    ls[t] = s; lq[t] = q; __syncthreads();
    if (sub < 4) { ls[t] += ls[t+4]; lq[t] += lq[t+4]; } __syncthreads();
    if (sub < 2) { ls[t] += ls[t+2]; lq[t] += lq[t+2]; } __syncthreads();
    if (sub == 0) {
        float ss = ls[t] + ls[t+1], qq = lq[t] + lq[t+1];
        float n = 8.0f * hw;
        float mu = ss / n;
        float var = qq / n - mu*mu;
        gmu[g] = mu; ginv[g] = rsqrtf(var + 1e-5f);
    }
    __syncthreads();
    int ch = t;
    float A = ginv[ch>>3] * gg[ch];
    float B = gb[ch] - gmu[ch>>3] * A;
    gnA[b*256 + ch] = A;
    gnB[b*256 + ch] = B;
}

__global__ __launch_bounds__(256) void gn_apply_kernel(const float* __restrict__ xbufT,
        const float* __restrict__ gnA, const float* __restrict__ gnB,
        const float* __restrict__ pos, float* __restrict__ src,
        short* __restrict__ srcbf, short* __restrict__ qbf, int hw, int sbase)
{
    int E = hw * 256;
    size_t fl = (size_t)blockIdx.x*1024 + threadIdx.x*4;
    int b = (int)(fl / E);
    int off = (int)(fl - (size_t)b*E);
    int p = off >> 8, col = off & 255;
    f32x4 v = *(const f32x4*)(xbufT + fl);
    f32x4 A = *(const f32x4*)(gnA + b*256 + col);
    f32x4 Bv = *(const f32x4*)(gnB + b*256 + col);
    size_t si = ((size_t)b*kS + sbase + p)*256 + col;
    f32x4 pv = *(const f32x4*)(pos + si);
    f32x4 o;
    o[0]=v[0]*A[0]+Bv[0]; o[1]=v[1]*A[1]+Bv[1];
    o[2]=v[2]*A[2]+Bv[2]; o[3]=v[3]*A[3]+Bv[3];
    *(f32x4*)(src + si) = o;
    short4v sb, qb;
    sb[0]=bf16rne(o[0]); sb[1]=bf16rne(o[1]); sb[2]=bf16rne(o[2]); sb[3]=bf16rne(o[3]);
    qb[0]=bf16rne(o[0]+pv[0]); qb[1]=bf16rne(o[1]+pv[1]);
    qb[2]=bf16rne(o[2]+pv[2]); qb[3]=bf16rne(o[3]+pv[3]);
    *(short4v*)(srcbf + si) = sb;
    *(short4v*)(qbf + si) = qb;
}

// single fused sine position embedding for all levels, broadcast over batch
__global__ __launch_bounds__(256) void pos_all_kernel(const float* __restrict__ lev,
                                                      float* __restrict__ pos)
{
    int idx = blockIdx.x * 256 + threadIdx.x;
    if (idx >= kS * 256) return;
    int ch = idx & 255;
    int p  = idx >> 8;
    int lvl, py, px, dim;
    if (p < 4096)      { lvl = 0; dim = 64; int l = p;        py = l >> 6; px = l & 63; }
    else if (p < 5120) { lvl = 1; dim = 32; int l = p - 4096; py = l >> 5; px = l & 31; }
    else if (p < 5376) { lvl = 2; dim = 16; int l = p - 5120; py = l >> 4; px = l & 15; }
    else               { lvl = 3; dim = 8;  int l = p - 5376; py = l >> 3; px = l & 7; }
    int c2 = ch & 127;
    int i  = c2 >> 1;
    float invdt = exp2f((float)i * -0.20762050593046015f);
    float t;
    if (ch < 128) t = (py + 1) / ((float)dim + 1e-6f) * 6.2831853071795864f;
    else          t = (px + 1) / ((float)dim + 1e-6f) * 6.2831853071795864f;
    float arg = t * invdt;
    float val = (c2 & 1) ? cosf(arg) : sinf(arg);
    val += lev[lvl*kH + ch];
    #pragma unroll
    for (int b = 0; b < kB; ++b)
        pos[(size_t)b*kS*256 + idx] = val;
}

// ---------------- BMx128 MFMA bf16 GEMM with 32x32x16 (BK=64) ----------------
template<int BM, int OUTMODE>
__global__ __launch_bounds__(256) void gemm32(const short* __restrict__ A,
        const short* __restrict__ W, const float* __restrict__ bias,
        float* __restrict__ C, short* __restrict__ Cb, int N, int K, int relu, int ncols)
{
    constexpr int FI = BM / 64;           // A frags per wave
    constexpr int NAV = (BM == 128) ? 4 : 2;
    __shared__ short Asm[2][BM * 40];
    __shared__ short Bsm[2][128 * 40];
    const int lin = xcd_swz(blockIdx.x, gridDim.x);
    const int bn  = (lin % ncols) * 128;
    const int bm  = (lin / ncols) * BM;
    const int t    = threadIdx.x;
    const int lane = t & 63;
    const int wid  = t >> 6;
    const int wr   = wid >> 1;
    const int wc   = wid & 1;
    const int l31  = lane & 31;
    const int hi8  = (lane >> 5) * 8;

    f32x16 acc[FI][2];
    #pragma unroll
    for (int i = 0; i < FI; ++i)
        #pragma unroll
        for (int j = 0; j < 2; ++j)
            acc[i][j] = (f32x16){0,0,0,0,0,0,0,0,0,0,0,0,0,0,0,0};

    int sa_r, sa_k;
    if constexpr (BM == 128) { sa_r = t >> 1; sa_k = (t & 1) * 32; }
    else                     { sa_r = t >> 2; sa_k = (t & 3) * 16; }
    const short* Aptr = A + (size_t)(bm + sa_r)*K + sa_k;
    const int sb_r = t >> 1;
    const int sb_k = (t & 1) * 32;
    const short* Wptr = W + (size_t)(bn + sb_r)*K + sb_k;

    short8v a[NAV], b[4];
    #pragma unroll
    for (int v = 0; v < NAV; ++v) a[v] = *(const short8v*)(Aptr + v*8);
    #pragma unroll
    for (int v = 0; v < 4; ++v)   b[v] = *(const short8v*)(Wptr + v*8);

    for (int k0 = 0; k0 < K; k0 += 64) {
        __syncthreads();
        if constexpr (BM == 128) {
            #pragma unroll
            for (int v = 0; v < 4; ++v) *(short8v*)&Asm[t & 1][LSWZ(sa_r, v*8)] = a[v];
        } else {
            #pragma unroll
            for (int v = 0; v < 2; ++v)
                *(short8v*)&Asm[sa_k >> 5][LSWZ(sa_r, (sa_k & 16) + v*8)] = a[v];
        }
        #pragma unroll
        for (int v = 0; v < 4; ++v) *(short8v*)&Bsm[t & 1][LSWZ(sb_r, v*8)] = b[v];
        __syncthreads();
        if (k0 + 64 < K) {
            #pragma unroll
            for (int v = 0; v < NAV; ++v) a[v] = *(const short8v*)(Aptr + k0 + 64 + v*8);
            #pragma unroll
            for (int v = 0; v < 4; ++v)   b[v] = *(const short8v*)(Wptr + k0 + 64 + v*8);
        }
        #pragma unroll
        for (int p = 0; p < 2; ++p)
            #pragma unroll
            for (int ks = 0; ks < 2; ++ks) {
                short8v af[FI], bfv[2];
                #pragma unroll
                for (int i = 0; i < FI; ++i)
                    af[i] = *(const short8v*)&Asm[p][LSWZ(wr*(BM/2) + i*32 + l31, ks*16 + hi8)];
                #pragma unroll
                for (int j = 0; j < 2; ++j)
                    bfv[j] = *(const short8v*)&Bsm[p][LSWZ(wc*64 + j*32 + l31, ks*16 + hi8)];
                #pragma unroll
                for (int i = 0; i < FI; ++i)
                    #pragma unroll
                    for (int j = 0; j < 2; ++j)
                        acc[i][j] = __builtin_amdgcn_mfma_f32_32x32x16_bf16(af[i], bfv[j], acc[i][j], 0, 0, 0);
            }
    }

    const int rbase = 4 * (lane >> 5);
    #pragma unroll
    for (int j = 0; j < 2; ++j) {
        int col = bn + wc*64 + j*32 + l31;
        float bz = bias[col];
        #pragma unroll
        for (int i = 0; i < FI; ++i) {
            int row0 = bm + wr*(BM/2) + i*32 + rbase;
            #pragma unroll
            for (int r = 0; r < 16; ++r) {
                int row = row0 + (r & 3) + 8*(r >> 2);
                float v = acc[i][j][r] + bz;
                if (relu) v = fmaxf(v, 0.f);
                if constexpr (OUTMODE == 0) C[(size_t)row*N + col] = v;
                else                        Cb[(size_t)row*N + col] = bf16rne(v);
            }
        }
    }
}

// merged (off|aw|val) GEMM, 32x32x16, BM=128. 1-D grid 5*(kM/128), XCD-swizzled.
// val tiles scatter into padded val layout via msdlut.
__global__ __launch_bounds__(256) void gemm_qv32(const short* __restrict__ Aq,
        const short* __restrict__ As, const short* __restrict__ W1,
        const short* __restrict__ W2, const float* __restrict__ b1,
        const float* __restrict__ b2, float* __restrict__ C1,
        short* __restrict__ Cb2, const int* __restrict__ msdlut)
{
    __shared__ short Asm[2][128 * 40];
    __shared__ short Bsm[2][128 * 40];
    const int lin = xcd_swz(blockIdx.x, gridDim.x);
    const int bn  = (lin % 5) * 128;
    const int bm  = (lin / 5) * 128;
    const bool qreg = bn < 384;
    const int K = 256;
    const int t    = threadIdx.x;
    const int lane = t & 63;
    const int wid  = t >> 6;
    const int wr   = wid >> 1;
    const int wc   = wid & 1;
    const int l31  = lane & 31;
    const int hi8  = (lane >> 5) * 8;
    const int sa_r = t >> 1;
    const int sa_p = t & 1;

    f32x16 acc[2][2];
    #pragma unroll
    for (int i = 0; i < 2; ++i)
        #pragma unroll
        for (int j = 0; j < 2; ++j)
            acc[i][j] = (f32x16){0,0,0,0,0,0,0,0,0,0,0,0,0,0,0,0};

    const short* Aptr = (qreg ? Aq : As) + (size_t)(bm + sa_r)*K + sa_p*32;
    const short* Wptr = (qreg ? (W1 + (size_t)(bn + sa_r)*K)
                              : (W2 + (size_t)(bn - 384 + sa_r)*K)) + sa_p*32;
    short8v a[4], b[4];
    #pragma unroll
    for (int v = 0; v < 4; ++v) { a[v] = *(const short8v*)(Aptr + v*8);
                                  b[v] = *(const short8v*)(Wptr + v*8); }

    for (int k0 = 0; k0 < K; k0 += 64) {
        __syncthreads();
        #pragma unroll
        for (int v = 0; v < 4; ++v) {
            *(short8v*)&Asm[sa_p][LSWZ(sa_r, v*8)] = a[v];
            *(short8v*)&Bsm[sa_p][LSWZ(sa_r, v*8)] = b[v];
        }
        __syncthreads();
        if (k0 + 64 < K) {
            #pragma unroll
            for (int v = 0; v < 4; ++v) {
                a[v] = *(const short8v*)(Aptr + k0 + 64 + v*8);
                b[v] = *(const short8v*)(Wptr + k0 + 64 + v*8);
            }
        }
        #pragma unroll
        for (int p = 0; p < 2; ++p)
            #pragma unroll
            for (int ks = 0; ks < 2; ++ks) {
                short8v af[2], bfv[2];
                #pragma unroll
                for (int i = 0; i < 2; ++i)
                    af[i] = *(const short8v*)&Asm[p][LSWZ(wr*64 + i*32 + l31, ks*16 + hi8)];
                #pragma unroll
                for (int j = 0; j < 2; ++j)
                    bfv[j] = *(const short8v*)&Bsm[p][LSWZ(wc*64 + j*32 + l31, ks*16 + hi8)];
                #pragma unroll
                for (int i = 0; i < 2; ++i)
                    #pragma unroll
                    for (int j = 0; j < 2; ++j)
                        acc[i][j] = __builtin_amdgcn_mfma_f32_32x32x16_bf16(af[i], bfv[j], acc[i][j], 0, 0, 0);
            }
    }

    const int rbase = 4 * (lane >> 5);
    if (bn == 256) {
        #pragma unroll
        for (int j = 0; j < 2; ++j) {
            int col = bn + wc*64 + j*32 + l31;
            float bz = b1[col];
            #pragma unroll
            for (int i = 0; i < 2; ++i) {
                int row0 = bm + wr*64 + i*32 + rbase;
                #pragma unroll
                for (int r = 0; r < 16; ++r) {
                    int row = row0 + (r & 3) + 8*(r >> 2);
                    float v = acc[i][j][r] + bz;
                    float m = v;
                    m = fmaxf(m, __shfl_xor(m, 1));
                    m = fmaxf(m, __shfl_xor(m, 2));
                    m = fmaxf(m, __shfl_xor(m, 4));
                    m = fmaxf(m, __shfl_xor(m, 8));
                    float e = expf(v - m);
                    float s = e;
                    s += __shfl_xor(s, 1);
                    s += __shfl_xor(s, 2);
                    s += __shfl_xor(s, 4);
                    s += __shfl_xor(s, 8);
                    C1[(size_t)row*384 + col] = e / s;
                }
            }
        }
    } else if (qreg) {
        #pragma unroll
        for (int j = 0; j < 2; ++j) {
            int col = bn + wc*64 + j*32 + l31;
            float bz = b1[col];
            #pragma unroll
            for (int i = 0; i < 2; ++i) {
                int row0 = bm + wr*64 + i*32 + rbase;
                #pragma unroll
                for (int r = 0; r < 16; ++r) {
                    int row = row0 + (r & 3) + 8*(r >> 2);
                    C1[(size_t)row*384 + col] = acc[i][j][r] + bz;
                }
            }
        }
    } else {
        // val tiles: scatter to padded layout
        #pragma unroll
        for (int j = 0; j < 2; ++j) {
            int col = bn + wc*64 + j*32 + l31 - 384;
            float bz = b2[col];
            #pragma unroll
            for (int i = 0; i < 2; ++i) {
                int row0 = bm + wr*64 + i*32 + rbase;
                #pragma unroll
                for (int r = 0; r < 16; ++r) {
                    int row = row0 + (r & 3) + 8*(r >> 2);
                    int prow = msdlut[row];
                    Cb2[(size_t)prow*256 + col] = bf16rne(acc[i][j][r] + bz);
                }
            }
        }
    }
}

// implicit-GEMM conv1 (16x16 structure, BM=128xBN=64): A from srcbf with (dy,dx) shifts.
__global__ __launch_bounds__(256) void conv1_gemm_kernel(const short* __restrict__ srcbf,
        const short* __restrict__ Wr, const float* __restrict__ bias,
        float* __restrict__ C)
{
    __shared__ short Asm[2][128 * 40];
    __shared__ short Bsm[2][64 * 40];
    const int t    = threadIdx.x;
    const int bm   = blockIdx.x * 128;
    const int K    = 2304;
    const int lane = t & 63;
    const int wid  = t >> 6;
    const int wr   = wid >> 1;
    const int wc   = wid & 1;
    const int frow = lane & 15;
    const int g    = lane >> 4;
    const int sa_r = t >> 1;
    const int sa_p = t & 1;

    const int m  = bm + sa_r;
    const int bb = m >> 12, ys = (m >> 6) & 63, xs = m & 63;

    f32x4 acc[4][2];
    #pragma unroll
    for (int i = 0; i < 4; ++i)
        #pragma unroll
        for (int j = 0; j < 2; ++j)
            acc[i][j] = (f32x4){0.f,0.f,0.f,0.f};

    auto loadA = [&](int k0, short8v* r) {
        int kk = k0 + sa_p*32;
        int kblk = kk >> 8;
        int dyy = kblk / 3, dxx = kblk - dyy*3;
        int yy = ys + dyy - 1, xx = xs + dxx - 1;
        if (yy >= 0 && yy < 64 && xx >= 0 && xx < 64) {
            const short* p = srcbf + ((size_t)(bb*kS + yy*64 + xx))*256 + (kk & 255);
            #pragma unroll
            for (int v = 0; v < 4; ++v) r[v] = *(const short8v*)(p + v*8);
        } else {
            #pragma unroll
            for (int v = 0; v < 4; ++v) r[v] = (short8v){0,0,0,0,0,0,0,0};
        }
    };

    const int sb_r = t >> 2, sb_p = (t & 3) >> 1, sb_o = (t & 1) * 16;
    const short* Wptr = Wr + (size_t)sb_r*K + (t & 3)*16;
    short8v a[4], b[2];
    loadA(0, a);
    b[0] = *(const short8v*)Wptr;
    b[1] = *(const short8v*)(Wptr + 8);

    for (int k0 = 0; k0 < K; k0 += 64) {
        __syncthreads();
        #pragma unroll
        for (int v = 0; v < 4; ++v) *(short8v*)&Asm[sa_p][sa_r*40 + v*8] = a[v];
        *(short8v*)&Bsm[sb_p][sb_r*40 + sb_o]     = b[0];
        *(short8v*)&Bsm[sb_p][sb_r*40 + sb_o + 8] = b[1];
        __syncthreads();
        if (k0 + 64 < K) {
            loadA(k0 + 64, a);
            b[0] = *(const short8v*)(Wptr + k0 + 64);
            b[1] = *(const short8v*)(Wptr + k0 + 72);
        }
        #pragma unroll
        for (int p = 0; p < 2; ++p) {
            short8v af[4], bfv[2];
            #pragma unroll
            for (int i = 0; i < 4; ++i)
                af[i] = *(const short8v*)&Asm[p][(wr*64 + i*16 + frow)*40 + g*8];
            #pragma unroll
            for (int j = 0; j < 2; ++j)
                bfv[j] = *(const short8v*)&Bsm[p][(wc*32 + j*16 + frow)*40 + g*8];
            #pragma unroll
            for (int i = 0; i < 4; ++i)
                #pragma unroll
                for (int j = 0; j < 2; ++j)
                    acc[i][j] = __builtin_amdgcn_mfma_f32_16x16x32_bf16(af[i], bfv[j], acc[i][j], 0, 0, 0);
        }
    }

    #pragma unroll
    for (int j = 0; j < 2; ++j) {
        int col = wc*32 + j*16 + frow;       // N = 64
        float bz = bias[col];
        #pragma unroll
        for (int i = 0; i < 4; ++i) {
            int row = bm + wr*64 + i*16 + g*4;
            #pragma unroll
            for (int rr = 0; rr < 4; ++rr) {
                float v = fmaxf(acc[i][j][rr] + bz, 0.f);
                C[(size_t)(row + rr)*64 + col] = v;
            }
        }
    }
}

// ms_deform on padded val: no validity mask (border zeros), clamp into pad.
// thread = (bs, head, d8); scalar FMAs; XCD-chunked blocks.
__global__ __launch_bounds__(256) void msdeform8_kernel(const short* __restrict__ valpad,
        const float* __restrict__ cat, short* __restrict__ msd)
{
    int blk  = xcd_swz(blockIdx.x, gridDim.x);
    int tid  = threadIdx.x;
    int d8   = tid & 3;
    int head = (tid >> 2) & 7;
    int bs   = blk*8 + (tid >> 5);
    int s  = bs % kS;
    int b  = bs / kS;
    float refx, refy;
    if (s < 4096)      { int loc = s;        refy = ((loc>>6)+0.5f)/64.f; refx = ((loc&63)+0.5f)/64.f; }
    else if (s < 5120) { int loc = s - 4096; refy = ((loc>>5)+0.5f)/32.f; refx = ((loc&31)+0.5f)/32.f; }
    else if (s < 5376) { int loc = s - 5120; refy = ((loc>>4)+0.5f)/16.f; refx = ((loc&15)+0.5f)/16.f; }
    else               { int loc = s - 5376; refy = ((loc>>3)+0.5f)/8.f;  refx = ((loc&7)+0.5f)/8.f; }
    const float* op = cat + (size_t)bs*384 + head*32;
    const float* ap = cat + (size_t)bs*384 + 256 + head*16;
    const short* vb = valpad + (size_t)b*kPad*256 + head*32 + d8*8;
    const int WL[4]  = {64,32,16,8};
    const int WL2[4] = {66,34,18,10};
    const int PB[4]  = {0,4356,5512,5836};
    float acc[8] = {0.f,0.f,0.f,0.f,0.f,0.f,0.f,0.f};
    #pragma unroll
    for (int l = 0; l < 4; ++l) {
        int wl = WL[l], wl2 = WL2[l], base = PB[l];
        float rxw = refx * wl - 0.5f;   // pow2-exact hoist
        float ryw = refy * wl - 0.5f;
        f32x4 o0 = *(const f32x4*)(op + l*8);
        f32x4 o1 = *(const f32x4*)(op + l*8 + 4);
        f32x4 av = *(const f32x4*)(ap + l*4);
        float oxs[4] = {o0[0], o0[2], o1[0], o1[2]};
        float oys[4] = {o0[1], o0[3], o1[1], o1[3]};
        #pragma unroll
        for (int p = 0; p < 4; ++p) {
            float gx = rxw + oxs[p];
            float gy = ryw + oys[p];
            float x0f = floorf(gx), y0f = floorf(gy);
            float wx1 = gx - x0f, wy1 = gy - y0f;
            int x1 = (int)x0f + 1, y1 = (int)y0f + 1;   // padded coords of (dx,dy)=(0,0)
            float a = av[p];
            #pragma unroll
            for (int dy = 0; dy < 2; ++dy) {
                int yp = min(max(y1 + dy, 0), wl + 1);
                float wya = (dy ? wy1 : 1.f - wy1) * a;
                #pragma unroll
                for (int dx = 0; dx < 2; ++dx) {
                    int xp = min(max(x1 + dx, 0), wl + 1);
                    float wgt = (dx ? wx1 : 1.f - wx1) * wya;
                    uint4 v = *(const uint4*)&vb[(size_t)(base + yp*wl2 + xp)*256];
                    acc[0] = fmaf(__uint_as_float(v.x << 16),          wgt, acc[0]);
                    acc[1] = fmaf(__uint_as_float(v.x & 0xffff0000u), wgt, acc[1]);
                    acc[2] = fmaf(__uint_as_float(v.y << 16),          wgt, acc[2]);
                    acc[3] = fmaf(__uint_as_float(v.y & 0xffff0000u), wgt, acc[3]);
                    acc[4] = fmaf(__uint_as_float(v.z << 16),          wgt, acc[4]);
                    acc[5] = fmaf(__uint_as_float(v.z & 0xffff0000u), wgt, acc[5]);
                    acc[6] = fmaf(__uint_as_float(v.w << 16),          wgt, acc[6]);
                    acc[7] = fmaf(__uint_as_float(v.w & 0xffff0000u), wgt, acc[7]);
                }
            }
        }
    }
    short8v o;
    #pragma unroll
    for (int k = 0; k < 8; ++k) o[k] = bf16rne(acc[k]);
    *(short8v*)&msd[(size_t)bs*256 + head*32 + d8*8] = o;
}

// src = LayerNorm(src + delta[bf16]); writes src fp32, srcbf, optionally qbf
template<int WQ>
__global__ __launch_bounds__(256) void add_ln_kernel(float* __restrict__ src,
        const short* __restrict__ delta, const float* __restrict__ g,
        const float* __restrict__ bta, short* __restrict__ srcbf,
        short* __restrict__ qbf, const float* __restrict__ pos)
{
    int lane = threadIdx.x & 63;
    int row  = blockIdx.x*4 + (threadIdx.x >> 6);
    f32x4* s4 = (f32x4*)(src + (size_t)row*256);
    f32x4 x = s4[lane];
    short4v dd = *(const short4v*)&delta[(size_t)row*256 + lane*4];
    x[0]+=bf2f(dd[0]); x[1]+=bf2f(dd[1]); x[2]+=bf2f(dd[2]); x[3]+=bf2f(dd[3]);
    float s = x[0]+x[1]+x[2]+x[3];
    #pragma unroll
    for (int o = 1; o < 64; o <<= 1) s += __shfl_xor(s, o);
    float mu = s * (1.f/256.f);
    f32x4 xc;
    xc[0]=x[0]-mu; xc[1]=x[1]-mu; xc[2]=x[2]-mu; xc[3]=x[3]-mu;
    float s2 = xc[0]*xc[0]+xc[1]*xc[1]+xc[2]*xc[2]+xc[3]*xc[3];
    #pragma unroll
    for (int o = 1; o < 64; o <<= 1) s2 += __shfl_xor(s2, o);
    float inv = rsqrtf(s2*(1.f/256.f) + 1e-5f);
    const f32x4 gv = ((const f32x4*)g)[lane];
    const f32x4 bv = ((const f32x4*)bta)[lane];
    f32x4 o4;
    o4[0]=xc[0]*inv*gv[0]+bv[0]; o4[1]=xc[1]*inv*gv[1]+bv[1];
    o4[2]=xc[2]*inv*gv[2]+bv[2]; o4[3]=xc[3]*inv*gv[3]+bv[3];
    s4[lane] = o4;
    short4v sb;
    sb[0]=bf16rne(o4[0]); sb[1]=bf16rne(o4[1]); sb[2]=bf16rne(o4[2]); sb[3]=bf16rne(o4[3]);
    *(short4v*)&srcbf[(size_t)row*256 + lane*4] = sb;
    if constexpr (WQ) {
        f32x4 pv = ((const f32x4*)(pos + (size_t)row*256))[lane];
        short4v qb;
        qb[0]=bf16rne(o4[0]+pv[0]); qb[1]=bf16rne(o4[1]+pv[1]);
        qb[2]=bf16rne(o4[2]+pv[2]); qb[3]=bf16rne(o4[3]+pv[3]);
        *(short4v*)&qbf[(size_t)row*256 + lane*4] = qb;
    }
}

// conv2: 3x3, 64->2; input c1 NHWC fp32; weights reordered [o][9][64]; output NCHW
__global__ void conv2_kernel(const float* __restrict__ c1, const float* __restrict__ w,
                             const float* __restrict__ bias, float* __restrict__ pred)
{
    int idx = blockIdx.x * blockDim.x + threadIdx.x;   // B*2*64*64
    int x = idx & 63;
    int y = (idx >> 6) & 63;
    int o = (idx >> 12) & 1;
    int b = idx >> 13;
    float acc = bias[o];
    #pragma unroll
    for (int dy = 0; dy < 3; ++dy) {
        int yy = y + dy - 1;
        if (yy < 0 || yy >= 64) continue;
        #pragma unroll
        for (int dx = 0; dx < 3; ++dx) {
            int xx = x + dx - 1;
            if (xx < 0 || xx >= 64) continue;
            const f32x4* sp = (const f32x4*)(c1 + ((size_t)(b*4096) + yy*64 + xx)*64);
            const f32x4* wp = (const f32x4*)(w + (o*9 + dy*3 + dx)*64);
            #pragma unroll
            for (int c = 0; c < 16; ++c) {
                f32x4 sv = sp[c], wv = wp[c];
                acc += sv[0]*wv[0] + sv[1]*wv[1] + sv[2]*wv[2] + sv[3]*wv[3];
            }
        }
    }
    pred[idx] = acc;
}

// bilinear resize 64x64 -> 256x256 (half-pixel, edge clamp)
__global__ void resize_kernel(const float* __restrict__ pred, float* __restrict__ out)
{
    int idx = blockIdx.x * blockDim.x + threadIdx.x;   // B*2*256*256
    int X = idx & 255;
    int Y = (idx >> 8) & 255;
    int c = (idx >> 16) & 1;
    int b = idx >> 17;
    float sx = (X + 0.5f)*0.25f - 0.5f;
    float sy = (Y + 0.5f)*0.25f - 0.5f;
    int x0 = (int)floorf(sx); float fx = sx - x0;
    int y0 = (int)floorf(sy); float fy = sy - y0;
    int x0c = min(max(x0, 0), 63), x1c = min(max(x0+1, 0), 63);
    int y0c = min(max(y0, 0), 63), y1c = min(max(y0+1, 0), 63);
    const float* p = pred + ((size_t)(b*2 + c))*4096;
    float v00 = p[y0c*64 + x0c], v01 = p[y0c*64 + x1c];
    float v10 = p[y1c*64 + x0c], v11 = p[y1c*64 + x1c];
    out[idx] = (1.f-fy)*((1.f-fx)*v00 + fx*v01) + fy*((1.f-fx)*v10 + fx*v11);
}

// ---------------- launch ----------------
extern "C" void kernel_launch(void* const* d_in, const int* in_sizes, int n_in,
                              void* d_out, int out_size, void* d_ws, size_t ws_size,
                              hipStream_t stream)
{
    const float* F[3][4];
    for (int t = 0; t < 3; ++t)
        for (int l = 0; l < 4; ++l)
            F[t][l] = (const float*)d_in[t*4 + l];
    const float* tfw = (const float*)d_in[12];
    const float *pw[4], *pb[4], *gg[4], *gb[4];
    for (int l = 0; l < 4; ++l) {
        pw[l] = (const float*)d_in[13 + 4*l];
        pb[l] = (const float*)d_in[14 + 4*l];
        gg[l] = (const float*)d_in[15 + 4*l];
        gb[l] = (const float*)d_in[16 + 4*l];
    }
    const float* lev   = (const float*)d_in[29];
    const float* off_w = (const float*)d_in[30];
    const float* off_b = (const float*)d_in[31];
    const float* aw_w  = (const float*)d_in[32];
    const float* aw_b  = (const float*)d_in[33];
    const float* val_w = (const float*)d_in[34];
    const float* val_b = (const float*)d_in[35];
    const float* out_w = (const float*)d_in[36];
    const float* out_b = (const float*)d_in[37];
    const float* ln1g  = (const float*)d_in[38];
    const float* ln1b  = (const float*)d_in[39];
    const float* ff1w  = (const float*)d_in[40];
    const float* ff1b  = (const float*)d_in[41];
    const float* ff2w  = (const float*)d_in[42];
    const float* ff2b  = (const float*)d_in[43];
    const float* ln2g  = (const float*)d_in[44];
    const float* ln2b  = (const float*)d_in[45];
    const float* c1w   = (const float*)d_in[46];
    const float* c1b   = (const float*)d_in[47];
    const float* c2w   = (const float*)d_in[48];
    const float* c2b   = (const float*)d_in[49];

    const size_t N256 = (size_t)kB * kS * 256;        // 5,570,560
    float* ws    = (float*)d_ws;
    float* src   = ws;                                // 5.57M f
    short* srcbf = (short*)(src + N256);
    short* qbf   = srcbf + N256;
    short* valpad= qbf + N256;                        // kPadShorts (6.08M shorts)
    short* msdbf = valpad + kPadShorts;
    short* warena= msdbf + N256;                      // bf16 weights
    short* Wcat_bf = warena;                              // 589824
    short* valw_bf = Wcat_bf + 589824;                    // 393216
    short* outw_bf = valw_bf + 393216;                    // 393216
    short* ff1w_bf = outw_bf + 393216;                    // 1572864
    short* ff2w_bf = ff1w_bf + 1572864;                   // 1572864
    short* pw_bf   = ff2w_bf + 1572864;                   // 360448
    short* c1w_bf  = pw_bf + 360448;                      // 147456 (reordered)
    float* bcat  = (float*)(c1w_bf + 147456 + 128);   // 2304 f
    float* gnstat= bcat + 4096;                       // 65536 f
    float* gnA   = gnstat + 65536;                    // 1024 f
    float* gnB   = gnA + 1024;                        // 1024 f
    float* c2wr  = gnB + 1024;                        // 1152 f
    int*   msdlut= (int*)(c2wr + 1280);               // kM ints
    float* pos   = (float*)(msdlut + 22016);          // 5.57M f
    float* cat   = pos + N256;                        // kM*384
    float* tmp   = cat + (size_t)kM*384;              // 5.57M f
    short* tmpbf = (short*)tmp;                       // bf16 view of tmp
    short* ffhbf = (short*)(tmp + N256);              // kM*1024 shorts
    // stage-1 aliases (cat/tmp dead in stage 1)
    short* fusedT = (short*)cat;
    float* xbufT  = tmp;
    // head aliases
    float* c1o   = (float*)valpad;                    // 16384*64 f fits in valpad+msdbf region
    float* pred  = (float*)msdbf;

    const int LVL_HWS[4]  = {4096, 1024, 256, 64};
    const int LVL_BASE[4] = {0, 4096, 5120, 5376};
    const int LVL_C[4]    = {128, 256, 512, 512};
    const int LVL_PRIOR[4]= {0, 128, 256, 512};       // reference's literal (non-cumulative) priors
    const int PW_OFF[4]   = {0, 32768, 98304, 229376};

    // ---- fused weight prep + msdlut + valpad zero (1 dispatch) ----
    prep_all_kernel<<<(kPrepThreads + 255)/256, 256, 0, stream>>>(
        off_w, aw_w, off_b, aw_b, val_w, out_w, ff1w, ff2w,
        pw[0], pw[1], pw[2], pw[3], c1w, c2w,
        Wcat_bf, bcat, valw_bf, outw_bf, ff1w_bf, ff2w_bf, pw_bf, c1w_bf, c2wr,
        msdlut, valpad);

    // ---- stage 1 ----
    pos_all_kernel<<<(kS*256 + 255)/256, 256, 0, stream>>>(lev, pos);
    for (int l = 0; l < 4; ++l) {
        int hw = LVL_HWS[l], c = LVL_C[l];
        dim3 gf(hw/32, c/32, kB);
        fuseT_kernel<<<gf, 256, 0, stream>>>(F[0][l], F[1][l], F[2][l], tfw,
                                             fusedT, c, hw, LVL_PRIOR[l]);
        int nwg = 2 * (kB*hw/64);
        gemm32<64,0><<<nwg, 256, 0, stream>>>(fusedT, pw_bf + PW_OFF[l], pb[l],
                                              xbufT, nullptr, 256, c, 0, 2);
        int nchunks = hw / 16;
        gn_sum_kernel<<<dim3(nchunks, kB), 256, 0, stream>>>(xbufT, gnstat, nchunks);
        gn_fin_kernel<<<kB, 256, 0, stream>>>(gnstat, gg[l], gb[l], gnA, gnB, nchunks, hw);
        gn_apply_kernel<<<(kB*hw*256)/1024, 256, 0, stream>>>(xbufT, gnA, gnB, pos,
                                                              src, srcbf, qbf, hw, LVL_BASE[l]);
    }

    // ---- stage 2: 6 encoder layers ----
    for (int i = 0; i < 6; ++i) {
        gemm_qv32<<<5*(kM/128), 256, 0, stream>>>(qbf, srcbf,
                Wcat_bf + (size_t)i*384*256, valw_bf + (size_t)i*65536,
                bcat + i*384, val_b + i*256, cat, valpad, msdlut);
        msdeform8_kernel<<<kM/8, 256, 0, stream>>>(valpad, cat, msdbf);
        gemm32<64,1><<<2*(kM/64), 256, 0, stream>>>(msdbf, outw_bf + (size_t)i*65536,
                                                    out_b + i*256, nullptr, tmpbf, 256, 256, 0, 2);
        add_ln_kernel<0><<<kM/4, 256, 0, stream>>>(src, tmpbf, ln1g + i*256, ln1b + i*256,
                                                   srcbf, nullptr, nullptr);
        gemm32<128,1><<<8*(kM/128), 256, 0, stream>>>(srcbf, ff1w_bf + (size_t)i*262144,
                                                      ff1b + i*1024, nullptr, ffhbf, 1024, 256, 1, 8);
        gemm32<64,1><<<2*(kM/64), 256, 0, stream>>>(ffhbf, ff2w_bf + (size_t)i*262144,
                                                    ff2b + i*256, nullptr, tmpbf, 256, 1024, 0, 2);
        if (i < 5)
            add_ln_kernel<1><<<kM/4, 256, 0, stream>>>(src, tmpbf, ln2g + i*256, ln2b + i*256,
                                                       srcbf, qbf, pos);
        else
            add_ln_kernel<0><<<kM/4, 256, 0, stream>>>(src, tmpbf, ln2g + i*256, ln2b + i*256,
                                                       srcbf, nullptr, nullptr);
    }

    // ---- stage 3: head ----
    {
        conv1_gemm_kernel<<<128, 256, 0, stream>>>(srcbf, c1w_bf, c1b, c1o);
        conv2_kernel<<<(kB*2*64*64)/256, 256, 0, stream>>>(c1o, c2wr, c2b, pred);
        resize_kernel<<<(kB*2*256*256)/256, 256, 0, stream>>>(pred, (float*)d_out);
    }
}

// Round 15
// 1061.515 us; speedup vs baseline: 1.4182x; 1.0068x over previous
//
#include <hip/hip_runtime.h>
#include <math.h>

// ---------------- problem constants ----------------
constexpr int kB = 4;
constexpr int kS = 5440;           // 64*64 + 32*32 + 16*16 + 8*8
constexpr int kH = 256;            // HIDDEN
constexpr int kNH = 8, kNL = 4, kNP = 4, kDH = 32;
constexpr int kM = kB * kS;        // 21760 rows
constexpr int kCHSUM = 1408;       // sum(CHS)
constexpr int kPad = 5936;         // padded S: 66^2 + 34^2 + 18^2 + 10^2
constexpr int kPadShorts = kB * kPad * 256;   // 6,078,464

typedef __attribute__((ext_vector_type(8))) short short8v;   // 8 bf16 (4 VGPRs)
typedef __attribute__((ext_vector_type(4))) short short4v;   // 4 bf16 (8 B)
typedef __attribute__((ext_vector_type(4))) float f32x4;
typedef __attribute__((ext_vector_type(16))) float f32x16;

__device__ inline short bf16rne(float f) {
    unsigned u = __float_as_uint(f);
    u += 0x7FFF + ((u >> 16) & 1);
    return (short)(u >> 16);
}
__device__ inline float bf2f(short s) {
    return __uint_as_float(((unsigned)(unsigned short)s) << 16);
}
// bijective XCD-chunked swizzle (m204): contiguous chunk per XCD
__device__ inline int xcd_swz(int orig, int nwg) {
    int q = nwg >> 3, r = nwg & 7;
    int x = orig & 7, o = orig >> 3;
    return (x < r ? x*(q+1) : r*(q+1) + (x-r)*q) + o;
}
// LDS offset with XOR swizzle: row stride 40 shorts, chunk in {0,8,16,24} shorts
#define LSWZ(row, chunk) ((row)*40 + ((chunk) ^ ((row) & 24)))

// ---------------- fused prep kernel (all weight conversions + lut + valpad zero) ----
__device__ inline void cv4(const float* __restrict__ in, short* __restrict__ out, int q)
{
    int i = q * 4;
    f32x4 v = *(const f32x4*)(in + i);
    short4v o;
    o[0]=bf16rne(v[0]); o[1]=bf16rne(v[1]); o[2]=bf16rne(v[2]); o[3]=bf16rne(v[3]);
    *(short4v*)(out + i) = o;
}
__global__ __launch_bounds__(256) void prep_all_kernel(
        const float* __restrict__ off_w, const float* __restrict__ aw_w,
        const float* __restrict__ off_b, const float* __restrict__ aw_b,
        const float* __restrict__ val_w, const float* __restrict__ out_w,
        const float* __restrict__ ff1w, const float* __restrict__ ff2w,
        const float* __restrict__ pw0, const float* __restrict__ pw1,
        const float* __restrict__ pw2, const float* __restrict__ pw3,
        const float* __restrict__ c1w, const float* __restrict__ c2w,
        short* __restrict__ Wcat, float* __restrict__ bcat,
        short* __restrict__ valwb, short* __restrict__ outwb,
        short* __restrict__ ff1wb, short* __restrict__ ff2wb,
        short* __restrict__ pwb, short* __restrict__ c1wb, float* __restrict__ c2wr,
        int* __restrict__ msdlut, short* __restrict__ valpad)
{
    int idx = blockIdx.x * 256 + threadIdx.x;
    if (idx < 589824) {                       // Wcat
        int col = idx & 255;
        int row = (idx >> 8) % 384;
        int i   = idx / (384*256);
        float v = (row < 256) ? off_w[((size_t)i*256 + row)*256 + col]
                              : aw_w[((size_t)i*128 + row-256)*256 + col];
        Wcat[idx] = bf16rne(v);
        return;
    }
    idx -= 589824;
    if (idx < 2304) {                         // bcat
        int row = idx % 384, i = idx / 384;
        bcat[idx] = (row < 256) ? off_b[i*256 + row] : aw_b[i*128 + row-256];
        return;
    }
    idx -= 2304;
    if (idx < 98304) { cv4(val_w, valwb, idx); return; }
    idx -= 98304;
    if (idx < 98304) { cv4(out_w, outwb, idx); return; }
    idx -= 98304;
    if (idx < 393216) { cv4(ff1w, ff1wb, idx); return; }
    idx -= 393216;
    if (idx < 393216) { cv4(ff2w, ff2wb, idx); return; }
    idx -= 393216;
    if (idx < 8192)  { cv4(pw0, pwb + 0,      idx); return; }
    idx -= 8192;
    if (idx < 16384) { cv4(pw1, pwb + 32768,  idx); return; }
    idx -= 16384;
    if (idx < 32768) { cv4(pw2, pwb + 98304,  idx); return; }
    idx -= 32768;
    if (idx < 32768) { cv4(pw3, pwb + 229376, idx); return; }
    idx -= 32768;
    if (idx < 147456) {                       // c1w reorder -> [o][(dy*3+dx)*256+c]
        int k = idx % 2304, o = idx / 2304;
        int kblk = k >> 8, c = k & 255;
        c1wb[idx] = bf16rne(c1w[(size_t)o*2304 + c*9 + kblk]);
        return;
    }
    idx -= 147456;
    if (idx < 1152) {                         // c2w reorder -> [o][9][64]
        int c = idx & 63, r = idx >> 6;
        int o = r / 9, kblk = r % 9;
        c2wr[idx] = c2w[((size_t)o*64 + c)*9 + kblk];
        return;
    }
    idx -= 1152;
    if (idx < kM) {                           // msdlut: bs -> padded row index
        int bs = idx;
        int b = bs / kS;
        int s = bs - b*kS;
        int pbase, wl2, py, px;
        if (s < 4096)      { pbase = 0;    wl2 = 66; int lo = s;        py = lo>>6; px = lo&63; }
        else if (s < 5120) { pbase = 4356; wl2 = 34; int lo = s - 4096; py = lo>>5; px = lo&31; }
        else if (s < 5376) { pbase = 5512; wl2 = 18; int lo = s - 5120; py = lo>>4; px = lo&15; }
        else               { pbase = 5836; wl2 = 10; int lo = s - 5376; py = lo>>3; px = lo&7; }
        msdlut[bs] = b*kPad + pbase + (py+1)*wl2 + (px+1);
        return;
    }
    idx -= kM;
    if (idx < kPadShorts/8) {                 // zero valpad (borders stay zero forever)
        short8v z = (short8v){0,0,0,0,0,0,0,0};
        *(short8v*)(valpad + (size_t)idx*8) = z;
    }
}
constexpr int kPrepThreads = 589824+2304+98304+98304+393216+393216+8192+16384+32768+32768+147456+1152
                           + kM + kPadShorts/8;

// ---------------- stage-1 kernels ----------------

__global__ __launch_bounds__(256) void fuseT_kernel(const float* __restrict__ f0,
        const float* __restrict__ f1, const float* __restrict__ f2,
        const float* __restrict__ tfw, short* __restrict__ out,
        int c, int hw, int prior)
{
    __shared__ float tile[32][33];
    int p0 = blockIdx.x * 32;
    int c0 = blockIdx.y * 32;
    int b  = blockIdx.z;
    int tx  = threadIdx.x & 31;
    int ty8 = threadIdx.x >> 5;
    #pragma unroll
    for (int i = 0; i < 4; ++i) {
        int ch = c0 + ty8 + i*8;
        float t0 = tfw[0*kCHSUM + prior + ch];
        float t1 = tfw[1*kCHSUM + prior + ch];
        float t2 = tfw[2*kCHSUM + prior + ch];
        float m = fmaxf(t0, fmaxf(t1, t2));
        float e0 = expf(t0-m), e1 = expf(t1-m), e2 = expf(t2-m);
        float inv = 1.0f / (e0+e1+e2);
        size_t base = ((size_t)b*c + ch)*hw + p0 + tx;
        tile[ty8+i*8][tx] = f0[base]*(e0*inv) + f1[base]*(e1*inv) + f2[base]*(e2*inv);
    }
    __syncthreads();
    #pragma unroll
    for (int i = 0; i < 4; ++i) {
        int p = p0 + ty8 + i*8;
        out[((size_t)b*hw + p)*c + c0 + tx] = bf16rne(tile[tx][ty8+i*8]);
    }
}

__global__ __launch_bounds__(256) void gn_sum_kernel(const float* __restrict__ xbufT,
        float* __restrict__ gnstat, int nchunks)
{
    int chunk = blockIdx.x, b = blockIdx.y;
    int t = threadIdx.x;
    size_t base = ((size_t)b*nchunks + chunk) * 4096;   // 16 rows * 256
    float s = 0.f, q = 0.f;
    #pragma unroll
    for (int i = 0; i < 4; ++i) {
        f32x4 v = *(const f32x4*)(xbufT + base + i*1024 + t*4);
        s += v[0]+v[1]+v[2]+v[3];
        q += v[0]*v[0]+v[1]*v[1]+v[2]*v[2]+v[3]*v[3];
    }
    __shared__ float ls[256], lq[256];
    ls[t] = s; lq[t] = q; __syncthreads();
    if (t < 64) { ls[t] += ls[t+64]+ls[t+128]+ls[t+192];
                  lq[t] += lq[t+64]+lq[t+128]+lq[t+192]; }
    __syncthreads();
    if (t < 32) {
        float ss = ls[2*t] + ls[2*t+1];
        float qq = lq[2*t] + lq[2*t+1];
        size_t o = (((size_t)b*nchunks + chunk)*32 + t)*2;
        gnstat[o] = ss; gnstat[o+1] = qq;
    }
}

__global__ __launch_bounds__(256) void gn_fin_kernel(const float* __restrict__ gnstat,
        const float* __restrict__ gg, const float* __restrict__ gb,
        float* __restrict__ gnA, float* __restrict__ gnB, int nchunks, int hw)
{
    int b = blockIdx.x, t = threadIdx.x;
    int g = t >> 3, sub = t & 7;
    float s = 0.f, q = 0.f;
    for (int c = sub; c < nchunks; c += 8) {
        size_t o = (((size_t)b*nchunks + c)*32 + g)*2;
        s += gnstat[o]; q += gnstat[o+1];
    }
    __shared__ float ls[256], lq[256], gmu[32], ginv[32];
    ls[t] = s; lq[t] = q; __syncthreads();
    if (sub < 4) { ls[t] += ls[t+4]; lq[t] += lq[t+4]; } __syncthreads();
    if (sub < 2) { ls[t] += ls[t+2]; lq[t] += lq[t+2]; } __syncthreads();
    if (sub == 0) {
        float ss = ls[t] + ls[t+1], qq = lq[t] + lq[t+1];
        float n = 8.0f * hw;
        float mu = ss / n;
        float var = qq / n - mu*mu;
        gmu[g] = mu; ginv[g] = rsqrtf(var + 1e-5f);
    }
    __syncthreads();
    int ch = t;
    float A = ginv[ch>>3] * gg[ch];
    float B = gb[ch] - gmu[ch>>3] * A;
    gnA[b*256 + ch] = A;
    gnB[b*256 + ch] = B;
}

__global__ __launch_bounds__(256) void gn_apply_kernel(const float* __restrict__ xbufT,
        const float* __restrict__ gnA, const float* __restrict__ gnB,
        const float* __restrict__ pos, float* __restrict__ src,
        short* __restrict__ srcbf, short* __restrict__ qbf, int hw, int sbase)
{
    int E = hw * 256;
    size_t fl = (size_t)blockIdx.x*1024 + threadIdx.x*4;
    int b = (int)(fl / E);
    int off = (int)(fl - (size_t)b*E);
    int p = off >> 8, col = off & 255;
    f32x4 v = *(const f32x4*)(xbufT + fl);
    f32x4 A = *(const f32x4*)(gnA + b*256 + col);
    f32x4 Bv = *(const f32x4*)(gnB + b*256 + col);
    size_t si = ((size_t)b*kS + sbase + p)*256 + col;
    f32x4 pv = *(const f32x4*)(pos + si);
    f32x4 o;
    o[0]=v[0]*A[0]+Bv[0]; o[1]=v[1]*A[1]+Bv[1];
    o[2]=v[2]*A[2]+Bv[2]; o[3]=v[3]*A[3]+Bv[3];
    *(f32x4*)(src + si) = o;
    short4v sb, qb;
    sb[0]=bf16rne(o[0]); sb[1]=bf16rne(o[1]); sb[2]=bf16rne(o[2]); sb[3]=bf16rne(o[3]);
    qb[0]=bf16rne(o[0]+pv[0]); qb[1]=bf16rne(o[1]+pv[1]);
    qb[2]=bf16rne(o[2]+pv[2]); qb[3]=bf16rne(o[3]+pv[3]);
    *(short4v*)(srcbf + si) = sb;
    *(short4v*)(qbf + si) = qb;
}

// single fused sine position embedding for all levels, broadcast over batch
__global__ __launch_bounds__(256) void pos_all_kernel(const float* __restrict__ lev,
                                                      float* __restrict__ pos)
{
    int idx = blockIdx.x * 256 + threadIdx.x;
    if (idx >= kS * 256) return;
    int ch = idx & 255;
    int p  = idx >> 8;
    int lvl, py, px, dim;
    if (p < 4096)      { lvl = 0; dim = 64; int l = p;        py = l >> 6; px = l & 63; }
    else if (p < 5120) { lvl = 1; dim = 32; int l = p - 4096; py = l >> 5; px = l & 31; }
    else if (p < 5376) { lvl = 2; dim = 16; int l = p - 5120; py = l >> 4; px = l & 15; }
    else               { lvl = 3; dim = 8;  int l = p - 5376; py = l >> 3; px = l & 7; }
    int c2 = ch & 127;
    int i  = c2 >> 1;
    float invdt = exp2f((float)i * -0.20762050593046015f);
    float t;
    if (ch < 128) t = (py + 1) / ((float)dim + 1e-6f) * 6.2831853071795864f;
    else          t = (px + 1) / ((float)dim + 1e-6f) * 6.2831853071795864f;
    float arg = t * invdt;
    float val = (c2 & 1) ? cosf(arg) : sinf(arg);
    val += lev[lvl*kH + ch];
    #pragma unroll
    for (int b = 0; b < kB; ++b)
        pos[(size_t)b*kS*256 + idx] = val;
}

// ---------------- BMx128 MFMA bf16 GEMM with 32x32x16 (BK=64) ----------------
template<int BM, int OUTMODE>
__global__ __launch_bounds__(256) void gemm32(const short* __restrict__ A,
        const short* __restrict__ W, const float* __restrict__ bias,
        float* __restrict__ C, short* __restrict__ Cb, int N, int K, int relu, int ncols)
{
    constexpr int FI = BM / 64;           // A frags per wave
    constexpr int NAV = (BM == 128) ? 4 : 2;
    __shared__ short Asm[2][BM * 40];
    __shared__ short Bsm[2][128 * 40];
    const int lin = xcd_swz(blockIdx.x, gridDim.x);
    const int bn  = (lin % ncols) * 128;
    const int bm  = (lin / ncols) * BM;
    const int t    = threadIdx.x;
    const int lane = t & 63;
    const int wid  = t >> 6;
    const int wr   = wid >> 1;
    const int wc   = wid & 1;
    const int l31  = lane & 31;
    const int hi8  = (lane >> 5) * 8;

    f32x16 acc[FI][2];
    #pragma unroll
    for (int i = 0; i < FI; ++i)
        #pragma unroll
        for (int j = 0; j < 2; ++j)
            acc[i][j] = (f32x16){0,0,0,0,0,0,0,0,0,0,0,0,0,0,0,0};

    int sa_r, sa_k;
    if constexpr (BM == 128) { sa_r = t >> 1; sa_k = (t & 1) * 32; }
    else                     { sa_r = t >> 2; sa_k = (t & 3) * 16; }
    const short* Aptr = A + (size_t)(bm + sa_r)*K + sa_k;
    const int sb_r = t >> 1;
    const int sb_k = (t & 1) * 32;
    const short* Wptr = W + (size_t)(bn + sb_r)*K + sb_k;

    short8v a[NAV], b[4];
    #pragma unroll
    for (int v = 0; v < NAV; ++v) a[v] = *(const short8v*)(Aptr + v*8);
    #pragma unroll
    for (int v = 0; v < 4; ++v)   b[v] = *(const short8v*)(Wptr + v*8);

    for (int k0 = 0; k0 < K; k0 += 64) {
        __syncthreads();
        if constexpr (BM == 128) {
            #pragma unroll
            for (int v = 0; v < 4; ++v) *(short8v*)&Asm[t & 1][LSWZ(sa_r, v*8)] = a[v];
        } else {
            #pragma unroll
            for (int v = 0; v < 2; ++v)
                *(short8v*)&Asm[sa_k >> 5][LSWZ(sa_r, (sa_k & 16) + v*8)] = a[v];
        }
        #pragma unroll
        for (int v = 0; v < 4; ++v) *(short8v*)&Bsm[t & 1][LSWZ(sb_r, v*8)] = b[v];
        __syncthreads();
        if (k0 + 64 < K) {
            #pragma unroll
            for (int v = 0; v < NAV; ++v) a[v] = *(const short8v*)(Aptr + k0 + 64 + v*8);
            #pragma unroll
            for (int v = 0; v < 4; ++v)   b[v] = *(const short8v*)(Wptr + k0 + 64 + v*8);
        }
        #pragma unroll
        for (int p = 0; p < 2; ++p)
            #pragma unroll
            for (int ks = 0; ks < 2; ++ks) {
                short8v af[FI], bfv[2];
                #pragma unroll
                for (int i = 0; i < FI; ++i)
                    af[i] = *(const short8v*)&Asm[p][LSWZ(wr*(BM/2) + i*32 + l31, ks*16 + hi8)];
                #pragma unroll
                for (int j = 0; j < 2; ++j)
                    bfv[j] = *(const short8v*)&Bsm[p][LSWZ(wc*64 + j*32 + l31, ks*16 + hi8)];
                #pragma unroll
                for (int i = 0; i < FI; ++i)
                    #pragma unroll
                    for (int j = 0; j < 2; ++j)
                        acc[i][j] = __builtin_amdgcn_mfma_f32_32x32x16_bf16(af[i], bfv[j], acc[i][j], 0, 0, 0);
            }
    }

    const int rbase = 4 * (lane >> 5);
    #pragma unroll
    for (int j = 0; j < 2; ++j) {
        int col = bn + wc*64 + j*32 + l31;
        float bz = bias[col];
        #pragma unroll
        for (int i = 0; i < FI; ++i) {
            int row0 = bm + wr*(BM/2) + i*32 + rbase;
            #pragma unroll
            for (int r = 0; r < 16; ++r) {
                int row = row0 + (r & 3) + 8*(r >> 2);
                float v = acc[i][j][r] + bz;
                if (relu) v = fmaxf(v, 0.f);
                if constexpr (OUTMODE == 0) C[(size_t)row*N + col] = v;
                else                        Cb[(size_t)row*N + col] = bf16rne(v);
            }
        }
    }
}

// merged (off|aw|val) GEMM, 32x32x16, BM=128. 1-D grid 5*(kM/128), XCD-swizzled.
// val tiles scatter into padded val layout via msdlut.
__global__ __launch_bounds__(256) void gemm_qv32(const short* __restrict__ Aq,
        const short* __restrict__ As, const short* __restrict__ W1,
        const short* __restrict__ W2, const float* __restrict__ b1,
        const float* __restrict__ b2, float* __restrict__ C1,
        short* __restrict__ Cb2, const int* __restrict__ msdlut)
{
    __shared__ short Asm[2][128 * 40];
    __shared__ short Bsm[2][128 * 40];
    const int lin = xcd_swz(blockIdx.x, gridDim.x);
    const int bn  = (lin % 5) * 128;
    const int bm  = (lin / 5) * 128;
    const bool qreg = bn < 384;
    const int K = 256;
    const int t    = threadIdx.x;
    const int lane = t & 63;
    const int wid  = t >> 6;
    const int wr   = wid >> 1;
    const int wc   = wid & 1;
    const int l31  = lane & 31;
    const int hi8  = (lane >> 5) * 8;
    const int sa_r = t >> 1;
    const int sa_p = t & 1;

    f32x16 acc[2][2];
    #pragma unroll
    for (int i = 0; i < 2; ++i)
        #pragma unroll
        for (int j = 0; j < 2; ++j)
            acc[i][j] = (f32x16){0,0,0,0,0,0,0,0,0,0,0,0,0,0,0,0};

    const short* Aptr = (qreg ? Aq : As) + (size_t)(bm + sa_r)*K + sa_p*32;
    const short* Wptr = (qreg ? (W1 + (size_t)(bn + sa_r)*K)
                              : (W2 + (size_t)(bn - 384 + sa_r)*K)) + sa_p*32;
    short8v a[4], b[4];
    #pragma unroll
    for (int v = 0; v < 4; ++v) { a[v] = *(const short8v*)(Aptr + v*8);
                                  b[v] = *(const short8v*)(Wptr + v*8); }

    for (int k0 = 0; k0 < K; k0 += 64) {
        __syncthreads();
        #pragma unroll
        for (int v = 0; v < 4; ++v) {
            *(short8v*)&Asm[sa_p][LSWZ(sa_r, v*8)] = a[v];
            *(short8v*)&Bsm[sa_p][LSWZ(sa_r, v*8)] = b[v];
        }
        __syncthreads();
        if (k0 + 64 < K) {
            #pragma unroll
            for (int v = 0; v < 4; ++v) {
                a[v] = *(const short8v*)(Aptr + k0 + 64 + v*8);
                b[v] = *(const short8v*)(Wptr + k0 + 64 + v*8);
            }
        }
        #pragma unroll
        for (int p = 0; p < 2; ++p)
            #pragma unroll
            for (int ks = 0; ks < 2; ++ks) {
                short8v af[2], bfv[2];
                #pragma unroll
                for (int i = 0; i < 2; ++i)
                    af[i] = *(const short8v*)&Asm[p][LSWZ(wr*64 + i*32 + l31, ks*16 + hi8)];
                #pragma unroll
                for (int j = 0; j < 2; ++j)
                    bfv[j] = *(const short8v*)&Bsm[p][LSWZ(wc*64 + j*32 + l31, ks*16 + hi8)];
                #pragma unroll
                for (int i = 0; i < 2; ++i)
                    #pragma unroll
                    for (int j = 0; j < 2; ++j)
                        acc[i][j] = __builtin_amdgcn_mfma_f32_32x32x16_bf16(af[i], bfv[j], acc[i][j], 0, 0, 0);
            }
    }

    const int rbase = 4 * (lane >> 5);
    if (bn == 256) {
        #pragma unroll
        for (int j = 0; j < 2; ++j) {
            int col = bn + wc*64 + j*32 + l31;
            float bz = b1[col];
            #pragma unroll
            for (int i = 0; i < 2; ++i) {
                int row0 = bm + wr*64 + i*32 + rbase;
                #pragma unroll
                for (int r = 0; r < 16; ++r) {
                    int row = row0 + (r & 3) + 8*(r >> 2);
                    float v = acc[i][j][r] + bz;
                    float m = v;
                    m = fmaxf(m, __shfl_xor(m, 1));
                    m = fmaxf(m, __shfl_xor(m, 2));
                    m = fmaxf(m, __shfl_xor(m, 4));
                    m = fmaxf(m, __shfl_xor(m, 8));
                    float e = expf(v - m);
                    float s = e;
                    s += __shfl_xor(s, 1);
                    s += __shfl_xor(s, 2);
                    s += __shfl_xor(s, 4);
                    s += __shfl_xor(s, 8);
                    C1[(size_t)row*384 + col] = e / s;
                }
            }
        }
    } else if (qreg) {
        #pragma unroll
        for (int j = 0; j < 2; ++j) {
            int col = bn + wc*64 + j*32 + l31;
            float bz = b1[col];
            #pragma unroll
            for (int i = 0; i < 2; ++i) {
                int row0 = bm + wr*64 + i*32 + rbase;
                #pragma unroll
                for (int r = 0; r < 16; ++r) {
                    int row = row0 + (r & 3) + 8*(r >> 2);
                    C1[(size_t)row*384 + col] = acc[i][j][r] + bz;
                }
            }
        }
    } else {
        // val tiles: scatter to padded layout
        #pragma unroll
        for (int j = 0; j < 2; ++j) {
            int col = bn + wc*64 + j*32 + l31 - 384;
            float bz = b2[col];
            #pragma unroll
            for (int i = 0; i < 2; ++i) {
                int row0 = bm + wr*64 + i*32 + rbase;
                #pragma unroll
                for (int r = 0; r < 16; ++r) {
                    int row = row0 + (r & 3) + 8*(r >> 2);
                    int prow = msdlut[row];
                    Cb2[(size_t)prow*256 + col] = bf16rne(acc[i][j][r] + bz);
                }
            }
        }
    }
}

// implicit-GEMM conv1, BM=64 x BN=64 (256 blocks -> full CU coverage).
// 16x16x32 frags; A from srcbf with (dy,dx) shifts; W reordered [64][(dy*3+dx)*256+c].
__global__ __launch_bounds__(256) void conv1_gemm_kernel(const short* __restrict__ srcbf,
        const short* __restrict__ Wr, const float* __restrict__ bias,
        float* __restrict__ C)
{
    __shared__ short Asm[2][64 * 40];
    __shared__ short Bsm[2][64 * 40];
    const int t    = threadIdx.x;
    const int bm   = blockIdx.x * 64;
    const int K    = 2304;
    const int lane = t & 63;
    const int wid  = t >> 6;
    const int wr   = wid >> 1;
    const int wc   = wid & 1;
    const int frow = lane & 15;
    const int g    = lane >> 4;
    const int sa_r = t >> 2;           // 0..63
    const int sa_k = (t & 3) * 16;     // 0,16,32,48

    const int m  = bm + sa_r;
    const int bb = m >> 12, ys = (m >> 6) & 63, xs = m & 63;

    f32x4 acc[2][2];
    #pragma unroll
    for (int i = 0; i < 2; ++i)
        #pragma unroll
        for (int j = 0; j < 2; ++j)
            acc[i][j] = (f32x4){0.f,0.f,0.f,0.f};

    auto loadA = [&](int k0, short8v* r) {
        int kk = k0 + sa_k;                  // 16-short run within one 256-block
        int kblk = kk >> 8;
        int dyy = kblk / 3, dxx = kblk - dyy*3;
        int yy = ys + dyy - 1, xx = xs + dxx - 1;
        if (yy >= 0 && yy < 64 && xx >= 0 && xx < 64) {
            const short* p = srcbf + ((size_t)(bb*kS + yy*64 + xx))*256 + (kk & 255);
            r[0] = *(const short8v*)p;
            r[1] = *(const short8v*)(p + 8);
        } else {
            r[0] = (short8v){0,0,0,0,0,0,0,0};
            r[1] = (short8v){0,0,0,0,0,0,0,0};
        }
    };

    const short* Wptr = Wr + (size_t)sa_r*K + sa_k;
    short8v a[2], b[2];
    loadA(0, a);
    b[0] = *(const short8v*)Wptr;
    b[1] = *(const short8v*)(Wptr + 8);

    for (int k0 = 0; k0 < K; k0 += 64) {
        __syncthreads();
        *(short8v*)&Asm[sa_k >> 5][sa_r*40 + (sa_k & 16)]     = a[0];
        *(short8v*)&Asm[sa_k >> 5][sa_r*40 + (sa_k & 16) + 8] = a[1];
        *(short8v*)&Bsm[sa_k >> 5][sa_r*40 + (sa_k & 16)]     = b[0];
        *(short8v*)&Bsm[sa_k >> 5][sa_r*40 + (sa_k & 16) + 8] = b[1];
        __syncthreads();
        if (k0 + 64 < K) {
            loadA(k0 + 64, a);
            b[0] = *(const short8v*)(Wptr + k0 + 64);
            b[1] = *(const short8v*)(Wptr + k0 + 72);
        }
        #pragma unroll
        for (int p = 0; p < 2; ++p) {
            short8v af[2], bfv[2];
            #pragma unroll
            for (int i = 0; i < 2; ++i)
                af[i] = *(const short8v*)&Asm[p][(wr*32 + i*16 + frow)*40 + g*8];
            #pragma unroll
            for (int j = 0; j < 2; ++j)
                bfv[j] = *(const short8v*)&Bsm[p][(wc*32 + j*16 + frow)*40 + g*8];
            #pragma unroll
            for (int i = 0; i < 2; ++i)
                #pragma unroll
                for (int j = 0; j < 2; ++j)
                    acc[i][j] = __builtin_amdgcn_mfma_f32_16x16x32_bf16(af[i], bfv[j], acc[i][j], 0, 0, 0);
        }
    }

    #pragma unroll
    for (int j = 0; j < 2; ++j) {
        int col = wc*32 + j*16 + frow;       // N = 64
        float bz = bias[col];
        #pragma unroll
        for (int i = 0; i < 2; ++i) {
            int row = bm + wr*32 + i*16 + g*4;
            #pragma unroll
            for (int rr = 0; rr < 4; ++rr) {
                float v = fmaxf(acc[i][j][rr] + bz, 0.f);
                C[(size_t)(row + rr)*64 + col] = v;
            }
        }
    }
}

// ms_deform on padded val: no validity mask (border zeros), clamp into pad.
__global__ __launch_bounds__(256) void msdeform8_kernel(const short* __restrict__ valpad,
        const float* __restrict__ cat, short* __restrict__ msd)
{
    int blk  = xcd_swz(blockIdx.x, gridDim.x);
    int tid  = threadIdx.x;
    int d8   = tid & 3;
    int head = (tid >> 2) & 7;
    int bs   = blk*8 + (tid >> 5);
    int s  = bs % kS;
    int b  = bs / kS;
    float refx, refy;
    if (s < 4096)      { int loc = s;        refy = ((loc>>6)+0.5f)/64.f; refx = ((loc&63)+0.5f)/64.f; }
    else if (s < 5120) { int loc = s - 4096; refy = ((loc>>5)+0.5f)/32.f; refx = ((loc&31)+0.5f)/32.f; }
    else if (s < 5376) { int loc = s - 5120; refy = ((loc>>4)+0.5f)/16.f; refx = ((loc&15)+0.5f)/16.f; }
    else               { int loc = s - 5376; refy = ((loc>>3)+0.5f)/8.f;  refx = ((loc&7)+0.5f)/8.f; }
    const float* op = cat + (size_t)bs*384 + head*32;
    const float* ap = cat + (size_t)bs*384 + 256 + head*16;
    const short* vb = valpad + (size_t)b*kPad*256 + head*32 + d8*8;
    const int WL[4]  = {64,32,16,8};
    const int WL2[4] = {66,34,18,10};
    const int PB[4]  = {0,4356,5512,5836};
    float acc[8] = {0.f,0.f,0.f,0.f,0.f,0.f,0.f,0.f};
    #pragma unroll
    for (int l = 0; l < 4; ++l) {
        int wl = WL[l], wl2 = WL2[l], base = PB[l];
        float rxw = refx * wl - 0.5f;   // pow2-exact hoist
        float ryw = refy * wl - 0.5f;
        f32x4 o0 = *(const f32x4*)(op + l*8);
        f32x4 o1 = *(const f32x4*)(op + l*8 + 4);
        f32x4 av = *(const f32x4*)(ap + l*4);
        float oxs[4] = {o0[0], o0[2], o1[0], o1[2]};
        float oys[4] = {o0[1], o0[3], o1[1], o1[3]};
        #pragma unroll
        for (int p = 0; p < 4; ++p) {
            float gx = rxw + oxs[p];
            float gy = ryw + oys[p];
            float x0f = floorf(gx), y0f = floorf(gy);
            float wx1 = gx - x0f, wy1 = gy - y0f;
            int x1 = (int)x0f + 1, y1 = (int)y0f + 1;   // padded coords of (dx,dy)=(0,0)
            float a = av[p];
            #pragma unroll
            for (int dy = 0; dy < 2; ++dy) {
                int yp = min(max(y1 + dy, 0), wl + 1);
                float wya = (dy ? wy1 : 1.f - wy1) * a;
                #pragma unroll
                for (int dx = 0; dx < 2; ++dx) {
                    int xp = min(max(x1 + dx, 0), wl + 1);
                    float wgt = (dx ? wx1 : 1.f - wx1) * wya;
                    uint4 v = *(const uint4*)&vb[(size_t)(base + yp*wl2 + xp)*256];
                    acc[0] = fmaf(__uint_as_float(v.x << 16),          wgt, acc[0]);
                    acc[1] = fmaf(__uint_as_float(v.x & 0xffff0000u), wgt, acc[1]);
                    acc[2] = fmaf(__uint_as_float(v.y << 16),          wgt, acc[2]);
                    acc[3] = fmaf(__uint_as_float(v.y & 0xffff0000u), wgt, acc[3]);
                    acc[4] = fmaf(__uint_as_float(v.z << 16),          wgt, acc[4]);
                    acc[5] = fmaf(__uint_as_float(v.z & 0xffff0000u), wgt, acc[5]);
                    acc[6] = fmaf(__uint_as_float(v.w << 16),          wgt, acc[6]);
                    acc[7] = fmaf(__uint_as_float(v.w & 0xffff0000u), wgt, acc[7]);
                }
            }
        }
    }
    short8v o;
    #pragma unroll
    for (int k = 0; k < 8; ++k) o[k] = bf16rne(acc[k]);
    *(short8v*)&msd[(size_t)bs*256 + head*32 + d8*8] = o;
}

// src = LayerNorm(src + delta[bf16]); writes src fp32, srcbf, optionally qbf
template<int WQ>
__global__ __launch_bounds__(256) void add_ln_kernel(float* __restrict__ src,
        const short* __restrict__ delta, const float* __restrict__ g,
        const float* __restrict__ bta, short* __restrict__ srcbf,
        short* __restrict__ qbf, const float* __restrict__ pos)
{
    int lane = threadIdx.x & 63;
    int row  = blockIdx.x*4 + (threadIdx.x >> 6);
    f32x4* s4 = (f32x4*)(src + (size_t)row*256);
    f32x4 x = s4[lane];
    short4v dd = *(const short4v*)&delta[(size_t)row*256 + lane*4];
    x[0]+=bf2f(dd[0]); x[1]+=bf2f(dd[1]); x[2]+=bf2f(dd[2]); x[3]+=bf2f(dd[3]);
    float s = x[0]+x[1]+x[2]+x[3];
    #pragma unroll
    for (int o = 1; o < 64; o <<= 1) s += __shfl_xor(s, o);
    float mu = s * (1.f/256.f);
    f32x4 xc;
    xc[0]=x[0]-mu; xc[1]=x[1]-mu; xc[2]=x[2]-mu; xc[3]=x[3]-mu;
    float s2 = xc[0]*xc[0]+xc[1]*xc[1]+xc[2]*xc[2]+xc[3]*xc[3];
    #pragma unroll
    for (int o = 1; o < 64; o <<= 1) s2 += __shfl_xor(s2, o);
    float inv = rsqrtf(s2*(1.f/256.f) + 1e-5f);
    const f32x4 gv = ((const f32x4*)g)[lane];
    const f32x4 bv = ((const f32x4*)bta)[lane];
    f32x4 o4;
    o4[0]=xc[0]*inv*gv[0]+bv[0]; o4[1]=xc[1]*inv*gv[1]+bv[1];
    o4[2]=xc[2]*inv*gv[2]+bv[2]; o4[3]=xc[3]*inv*gv[3]+bv[3];
    s4[lane] = o4;
    short4v sb;
    sb[0]=bf16rne(o4[0]); sb[1]=bf16rne(o4[1]); sb[2]=bf16rne(o4[2]); sb[3]=bf16rne(o4[3]);
    *(short4v*)&srcbf[(size_t)row*256 + lane*4] = sb;
    if constexpr (WQ) {
        f32x4 pv = ((const f32x4*)(pos + (size_t)row*256))[lane];
        short4v qb;
        qb[0]=bf16rne(o4[0]+pv[0]); qb[1]=bf16rne(o4[1]+pv[1]);
        qb[2]=bf16rne(o4[2]+pv[2]); qb[3]=bf16rne(o4[3]+pv[3]);
        *(short4v*)&qbf[(size_t)row*256 + lane*4] = qb;
    }
}

// conv2: 3x3, 64->2; input c1 NHWC fp32; weights reordered [o][9][64]; output NCHW
__global__ void conv2_kernel(const float* __restrict__ c1, const float* __restrict__ w,
                             const float* __restrict__ bias, float* __restrict__ pred)
{
    int idx = blockIdx.x * blockDim.x + threadIdx.x;   // B*2*64*64
    int x = idx & 63;
    int y = (idx >> 6) & 63;
    int o = (idx >> 12) & 1;
    int b = idx >> 13;
    float acc = bias[o];
    #pragma unroll
    for (int dy = 0; dy < 3; ++dy) {
        int yy = y + dy - 1;
        if (yy < 0 || yy >= 64) continue;
        #pragma unroll
        for (int dx = 0; dx < 3; ++dx) {
            int xx = x + dx - 1;
            if (xx < 0 || xx >= 64) continue;
            const f32x4* sp = (const f32x4*)(c1 + ((size_t)(b*4096) + yy*64 + xx)*64);
            const f32x4* wp = (const f32x4*)(w + (o*9 + dy*3 + dx)*64);
            #pragma unroll
            for (int c = 0; c < 16; ++c) {
                f32x4 sv = sp[c], wv = wp[c];
                acc += sv[0]*wv[0] + sv[1]*wv[1] + sv[2]*wv[2] + sv[3]*wv[3];
            }
        }
    }
    pred[idx] = acc;
}

// bilinear resize 64x64 -> 256x256 (half-pixel, edge clamp)
__global__ void resize_kernel(const float* __restrict__ pred, float* __restrict__ out)
{
    int idx = blockIdx.x * blockDim.x + threadIdx.x;   // B*2*256*256
    int X = idx & 255;
    int Y = (idx >> 8) & 255;
    int c = (idx >> 16) & 1;
    int b = idx >> 17;
    float sx = (X + 0.5f)*0.25f - 0.5f;
    float sy = (Y + 0.5f)*0.25f - 0.5f;
    int x0 = (int)floorf(sx); float fx = sx - x0;
    int y0 = (int)floorf(sy); float fy = sy - y0;
    int x0c = min(max(x0, 0), 63), x1c = min(max(x0+1, 0), 63);
    int y0c = min(max(y0, 0), 63), y1c = min(max(y0+1, 0), 63);
    const float* p = pred + ((size_t)(b*2 + c))*4096;
    float v00 = p[y0c*64 + x0c], v01 = p[y0c*64 + x1c];
    float v10 = p[y1c*64 + x0c], v11 = p[y1c*64 + x1c];
    out[idx] = (1.f-fy)*((1.f-fx)*v00 + fx*v01) + fy*((1.f-fx)*v10 + fx*v11);
}

// ---------------- launch ----------------
extern "C" void kernel_launch(void* const* d_in, const int* in_sizes, int n_in,
                              void* d_out, int out_size, void* d_ws, size_t ws_size,
                              hipStream_t stream)
{
    const float* F[3][4];
    for (int t = 0; t < 3; ++t)
        for (int l = 0; l < 4; ++l)
            F[t][l] = (const float*)d_in[t*4 + l];
    const float* tfw = (const float*)d_in[12];
    const float *pw[4], *pb[4], *gg[4], *gb[4];
    for (int l = 0; l < 4; ++l) {
        pw[l] = (const float*)d_in[13 + 4*l];
        pb[l] = (const float*)d_in[14 + 4*l];
        gg[l] = (const float*)d_in[15 + 4*l];
        gb[l] = (const float*)d_in[16 + 4*l];
    }
    const float* lev   = (const float*)d_in[29];
    const float* off_w = (const float*)d_in[30];
    const float* off_b = (const float*)d_in[31];
    const float* aw_w  = (const float*)d_in[32];
    const float* aw_b  = (const float*)d_in[33];
    const float* val_w = (const float*)d_in[34];
    const float* val_b = (const float*)d_in[35];
    const float* out_w = (const float*)d_in[36];
    const float* out_b = (const float*)d_in[37];
    const float* ln1g  = (const float*)d_in[38];
    const float* ln1b  = (const float*)d_in[39];
    const float* ff1w  = (const float*)d_in[40];
    const float* ff1b  = (const float*)d_in[41];
    const float* ff2w  = (const float*)d_in[42];
    const float* ff2b  = (const float*)d_in[43];
    const float* ln2g  = (const float*)d_in[44];
    const float* ln2b  = (const float*)d_in[45];
    const float* c1w   = (const float*)d_in[46];
    const float* c1b   = (const float*)d_in[47];
    const float* c2w   = (const float*)d_in[48];
    const float* c2b   = (const float*)d_in[49];

    const size_t N256 = (size_t)kB * kS * 256;        // 5,570,560
    float* ws    = (float*)d_ws;
    float* src   = ws;                                // 5.57M f
    short* srcbf = (short*)(src + N256);
    short* qbf   = srcbf + N256;
    short* valpad= qbf + N256;                        // kPadShorts (6.08M shorts)
    short* msdbf = valpad + kPadShorts;
    short* warena= msdbf + N256;                      // bf16 weights
    short* Wcat_bf = warena;                              // 589824
    short* valw_bf = Wcat_bf + 589824;                    // 393216
    short* outw_bf = valw_bf + 393216;                    // 393216
    short* ff1w_bf = outw_bf + 393216;                    // 1572864
    short* ff2w_bf = ff1w_bf + 1572864;                   // 1572864
    short* pw_bf   = ff2w_bf + 1572864;                   // 360448
    short* c1w_bf  = pw_bf + 360448;                      // 147456 (reordered)
    float* bcat  = (float*)(c1w_bf + 147456 + 128);   // 2304 f
    float* gnstat= bcat + 4096;                       // 65536 f
    float* gnA   = gnstat + 65536;                    // 1024 f
    float* gnB   = gnA + 1024;                        // 1024 f
    float* c2wr  = gnB + 1024;                        // 1152 f
    int*   msdlut= (int*)(c2wr + 1280);               // kM ints
    float* pos   = (float*)(msdlut + 22016);          // 5.57M f
    float* cat   = pos + N256;                        // kM*384
    float* tmp   = cat + (size_t)kM*384;              // 5.57M f
    short* tmpbf = (short*)tmp;                       // bf16 view of tmp
    short* ffhbf = (short*)(tmp + N256);              // kM*1024 shorts
    // stage-1 aliases (cat/tmp dead in stage 1)
    short* fusedT = (short*)cat;
    float* xbufT  = tmp;
    // head aliases
    float* c1o   = (float*)valpad;                    // 16384*64 f fits in valpad+msdbf region
    float* pred  = (float*)msdbf;

    const int LVL_HWS[4]  = {4096, 1024, 256, 64};
    const int LVL_BASE[4] = {0, 4096, 5120, 5376};
    const int LVL_C[4]    = {128, 256, 512, 512};
    const int LVL_PRIOR[4]= {0, 128, 256, 512};       // reference's literal (non-cumulative) priors
    const int PW_OFF[4]   = {0, 32768, 98304, 229376};

    // ---- fused weight prep + msdlut + valpad zero (1 dispatch) ----
    prep_all_kernel<<<(kPrepThreads + 255)/256, 256, 0, stream>>>(
        off_w, aw_w, off_b, aw_b, val_w, out_w, ff1w, ff2w,
        pw[0], pw[1], pw[2], pw[3], c1w, c2w,
        Wcat_bf, bcat, valw_bf, outw_bf, ff1w_bf, ff2w_bf, pw_bf, c1w_bf, c2wr,
        msdlut, valpad);

    // ---- stage 1 ----
    pos_all_kernel<<<(kS*256 + 255)/256, 256, 0, stream>>>(lev, pos);
    for (int l = 0; l < 4; ++l) {
        int hw = LVL_HWS[l], c = LVL_C[l];
        dim3 gf(hw/32, c/32, kB);
        fuseT_kernel<<<gf, 256, 0, stream>>>(F[0][l], F[1][l], F[2][l], tfw,
                                             fusedT, c, hw, LVL_PRIOR[l]);
        int nwg = 2 * (kB*hw/64);
        gemm32<64,0><<<nwg, 256, 0, stream>>>(fusedT, pw_bf + PW_OFF[l], pb[l],
                                              xbufT, nullptr, 256, c, 0, 2);
        int nchunks = hw / 16;
        gn_sum_kernel<<<dim3(nchunks, kB), 256, 0, stream>>>(xbufT, gnstat, nchunks);
        gn_fin_kernel<<<kB, 256, 0, stream>>>(gnstat, gg[l], gb[l], gnA, gnB, nchunks, hw);
        gn_apply_kernel<<<(kB*hw*256)/1024, 256, 0, stream>>>(xbufT, gnA, gnB, pos,
                                                              src, srcbf, qbf, hw, LVL_BASE[l]);
    }

    // ---- stage 2: 6 encoder layers ----
    for (int i = 0; i < 6; ++i) {
        gemm_qv32<<<5*(kM/128), 256, 0, stream>>>(qbf, srcbf,
                Wcat_bf + (size_t)i*384*256, valw_bf + (size_t)i*65536,
                bcat + i*384, val_b + i*256, cat, valpad, msdlut);
        msdeform8_kernel<<<kM/8, 256, 0, stream>>>(valpad, cat, msdbf);
        gemm32<64,1><<<2*(kM/64), 256, 0, stream>>>(msdbf, outw_bf + (size_t)i*65536,
                                                    out_b + i*256, nullptr, tmpbf, 256, 256, 0, 2);
        add_ln_kernel<0><<<kM/4, 256, 0, stream>>>(src, tmpbf, ln1g + i*256, ln1b + i*256,
                                                   srcbf, nullptr, nullptr);
        gemm32<128,1><<<8*(kM/128), 256, 0, stream>>>(srcbf, ff1w_bf + (size_t)i*262144,
                                                      ff1b + i*1024, nullptr, ffhbf, 1024, 256, 1, 8);
        gemm32<64,1><<<2*(kM/64), 256, 0, stream>>>(ffhbf, ff2w_bf + (size_t)i*262144,
                                                    ff2b + i*256, nullptr, tmpbf, 256, 1024, 0, 2);
        if (i < 5)
            add_ln_kernel<1><<<kM/4, 256, 0, stream>>>(src, tmpbf, ln2g + i*256, ln2b + i*256,
                                                       srcbf, qbf, pos);
        else
            add_ln_kernel<0><<<kM/4, 256, 0, stream>>>(src, tmpbf, ln2g + i*256, ln2b + i*256,
                                                       srcbf, nullptr, nullptr);
    }

    // ---- stage 3: head ----
    {
        conv1_gemm_kernel<<<256, 256, 0, stream>>>(srcbf, c1w_bf, c1b, c1o);
        conv2_kernel<<<(kB*2*64*64)/256, 256, 0, stream>>>(c1o, c2wr, c2b, pred);
        resize_kernel<<<(kB*2*256*256)/256, 256, 0, stream>>>(pred, (float*)d_out);
    }
}